// Round 9
// baseline (364.150 us; speedup 1.0000x reference)
//
#include <hip/hip_runtime.h>
#include <hip/hip_bf16.h>
#include <math.h>

#define TT  100
#define CIN 400
#define H1  256
#define NS  32
#define NP  96
#define H3  512
#define H2C 128
#define BB  2
#define IJ  10000
#define NVALID 5050
#define PADW 102
#define PPIX 10432
#define PSTRIDE (PPIX * H2C)

typedef __attribute__((ext_vector_type(8))) short bf16x8;
typedef __attribute__((ext_vector_type(4))) float f32x4;

// ---- static scratch (float units) ----
#define OFF_XT   0
#define OFF_H1   80000
#define OFF_H2   131200
#define OFF_SB   182400
#define OFF_EB   233600
#define OFF_PF   284800
#define OFF_ATB  336000      // bf16 pair-words ATb[b][32][3200][4 quarters x 16B]
#define OFF_CM2T 3612800     // bf16 [b][ij][512] (valid rows only)
#define OFF_P1   8732800
#define OFF_P2   10068096
#define OFF_CINV 11403392    // uint[64]: c_inv as bf16 pairs
#define OFF_WQ1B 12683392
#define OFF_WQ2B 12716160
#define OFF_WQ3B 12789888
#define OFF_DESC 12863616    // u32 [96][10240]
#define OFF_PFT  13846656    // bf16 [b][112][256]
#define OFF_W3B  13875328    // bf16 [n][o][c]
#define G_TOTAL  15972480

__device__ __align__(16) float g_buf[G_TOTAL];

__device__ inline unsigned short f2bf(float f) {
    __hip_bfloat16 h = __float2bfloat16(f);
    return *(unsigned short*)&h;
}
__device__ inline float bf2f(unsigned short u) {
    union { unsigned int i; float f; } v; v.i = ((unsigned int)u) << 16; return v.f;
}
__device__ inline void dot2(float& acc, unsigned int a, unsigned int w) {
    asm("v_dot2_f32_bf16 %0, %1, %2, %0" : "+v"(acc) : "v"(a), "v"(w));
}

// ---------- merged prep ----------
__global__ void k_prep(const float* __restrict__ wq1, const float* __restrict__ wq2,
                       const float* __restrict__ wq3, const float* __restrict__ x,
                       const float* __restrict__ b3d, const float* __restrict__ bq1) {
    int id = blockIdx.x * 256 + threadIdx.x;
    if (id < 65536) {
        ((unsigned short*)(g_buf + OFF_WQ1B))[id] = f2bf(wq1[id]);
        return;
    }
    id -= 65536;
    if (id < 147456) {
        int q = id / 1152, k = id % 1152, tap = k >> 7, c = k & 127;
        ((unsigned short*)(g_buf + OFF_WQ2B))[id] = f2bf(wq2[(q * 128 + c) * 9 + tap]);
        return;
    }
    id -= 147456;
    if (id < 147456) {
        int q = id / 1152, k = id % 1152, tap = k >> 7, c = k & 127;
        ((unsigned short*)(g_buf + OFF_WQ3B))[id] = f2bf(wq3[(q * 128 + c) * 9 + tap]);
        return;
    }
    id -= 147456;
    if (id < 51712) {   // halo zero
        int c = id & 31;
        int h = (id >> 5) % 404;
        int bb = ((id >> 5) / 404) & 1;
        int buf = id / 25856;
        int pix;
        if (h < 102) pix = h;
        else if (h < 204) pix = 101 * PADW + (h - 102);
        else { int q = h - 204; pix = (1 + (q >> 1)) * PADW + ((q & 1) ? 101 : 0); }
        unsigned short* P = (unsigned short*)(g_buf + (buf ? OFF_P2 : OFF_P1))
                            + (size_t)bb * PSTRIDE + (size_t)pix * H2C;
        ((uint2*)P)[c] = make_uint2(0u, 0u);
        return;
    }
    id -= 51712;
    if (id < NP * 10240) {   // desc
        int k = id / 10240, q = id - k * 10240;
        int i = q / 100, j = q - i * 100;
        unsigned int nb = (unsigned int)((k / 3) * 100);
        unsigned int d;
        if (q >= IJ || i > j) {
            d = nb | (2u << 12);
        } else {
            double len = (double)(j - i + 2);
            double xmn = (double)i - 0.5 * len;
            double xmx = (double)(j + 1) + 0.5 * len;
            double plen = (xmx - xmn) / 95.0;
            double s = __dadd_rn(xmn, __dmul_rn(plen, (double)k));
            double tr = trunc(s);
            double dec = s - tr;
            int dn = (int)tr;
            int up = (int)ceil(s);
            bool okd = (unsigned)dn < (unsigned)TT;
            bool oku = (unsigned)up < (unsigned)TT;
            if (!okd) d = nb | (2u << 12);
            else if (oku && up == dn + 1) {
                unsigned int dfx = (unsigned int)__double2int_rn(dec * 65535.0);
                d = (nb + dn) | (dfx << 16);
            } else if (oku) {
                d = (nb + dn) | (1u << 12);
            } else {
                unsigned int dfx = (unsigned int)__double2int_rn(dec * 65535.0);
                d = (nb + dn) | (1u << 12) | (dfx << 16);
            }
        }
        ((unsigned int*)(g_buf + OFF_DESC))[id] = d;
        return;
    }
    id -= NP * 10240;
    if (id < BB * TT * CIN) {   // x transpose
        int c = id % CIN, t = (id / CIN) % TT, b = id / (CIN * TT);
        g_buf[OFF_XT + (b * CIN + c) * TT + t] = x[id];
        return;
    }
    id -= BB * TT * CIN;
    if (id < BB * 12 * 256) {   // zero pfT pad rows
        int c = id & 255, tp = (id >> 8) % 12, b = id / (12 * 256);
        ((unsigned short*)(g_buf + OFF_PFT))[((size_t)b * 112 + 100 + tp) * 256 + c] = 0;
        return;
    }
    id -= BB * 12 * 256;
    if (id < 128) {   // c_inv[q] = relu(wq1 . relu(b3d) + bq1), packed bf16 pairs
        int q = id;
        float acc = bq1[q];
        const float* wr = wq1 + q * 512;
        #pragma unroll 8
        for (int c = 0; c < 512; ++c) acc = fmaf(wr[c], fmaxf(b3d[c], 0.f), acc);
        acc = fmaxf(acc, 0.f);
        float accO = __shfl_xor(acc, 1);
        if ((id & 1) == 0)
            ((unsigned int*)(g_buf + OFF_CINV))[id >> 1] =
                (unsigned int)f2bf(acc) | ((unsigned int)f2bf(accO) << 16);
    }
}
#define PREP_IDS (65536 + 147456 + 147456 + 51712 + NP * 10240 + BB * TT * CIN + BB * 12 * 256 + 128)

// ---------- conv1d k=3 pad=1 + relu (3 acc chains) ----------
template<int IPG, int OPG, int CINTOT>
__global__ void k_conv_t(int in_off, const float* __restrict__ w,
                         const float* __restrict__ bias, int out_off) {
    int id = blockIdx.x * 256 + threadIdx.x;
    if (id >= BB * H1 * TT) return;
    int t = id % TT, o = (id / TT) % H1, b = id / (TT * H1);
    const float* ip = g_buf + in_off + (b * CINTOT + (o / OPG) * IPG) * TT + t;
    const float* wp = w + o * IPG * 3;
    float a0 = bias[o], a1 = 0.f, a2 = 0.f;
    bool t0 = (t > 0), t1 = (t < TT - 1);
    #pragma unroll 4
    for (int ci = 0; ci < IPG; ++ci) {
        float v0 = t0 ? ip[ci * TT - 1] : 0.f;
        float v1 = ip[ci * TT];
        float v2 = t1 ? ip[ci * TT + 1] : 0.f;
        a0 = fmaf(v0, wp[ci * 3 + 0], a0);
        a1 = fmaf(v1, wp[ci * 3 + 1], a1);
        a2 = fmaf(v2, wp[ci * 3 + 2], a2);
    }
    g_buf[out_off + id] = fmaxf(a0 + a1 + a2, 0.f);
}

// ---------- s & e convs merged ----------
__global__ void k_conv_se(const float* __restrict__ ws1, const float* __restrict__ bs1,
                          const float* __restrict__ we1, const float* __restrict__ be1) {
    int sec = blockIdx.x >= 200;
    int id = (blockIdx.x - sec * 200) * 256 + threadIdx.x;
    if (id >= BB * H1 * TT) return;
    const float* w  = sec ? we1 : ws1;
    const float* bi = sec ? be1 : bs1;
    int out_off = sec ? OFF_EB : OFF_SB;
    int t = id % TT, o = (id / TT) % H1, b = id / (TT * H1);
    const float* ip = g_buf + OFF_H2 + (b * H1 + (o / 64) * 64) * TT + t;
    const float* wp = w + o * 64 * 3;
    float a0 = bi[o], a1 = 0.f, a2 = 0.f;
    bool tl = (t > 0), th = (t < TT - 1);
    #pragma unroll 4
    for (int ci = 0; ci < 64; ++ci) {
        float v0 = tl ? ip[ci * TT - 1] : 0.f;
        float v1 = ip[ci * TT];
        float v2 = th ? ip[ci * TT + 1] : 0.f;
        a0 = fmaf(v0, wp[ci * 3 + 0], a0);
        a1 = fmaf(v1, wp[ci * 3 + 1], a1);
        a2 = fmaf(v2, wp[ci * 3 + 2], a2);
    }
    g_buf[out_off + id] = fmaxf(a0 + a1 + a2, 0.f);
}

// ---------- pf conv writing pfT bf16 directly ----------
__global__ void k_conv_pf(const float* __restrict__ w, const float* __restrict__ bias) {
    int id = blockIdx.x * 256 + threadIdx.x;
    if (id >= BB * H1 * TT) return;
    int t = id % TT, o = (id / TT) % H1, b = id / (TT * H1);
    const float* ip = g_buf + OFF_H2 + (b * H1) * TT + t;
    const float* wp = w + o * H1 * 3;
    float a0 = bias[o], a1 = 0.f, a2 = 0.f;
    bool tl = (t > 0), th = (t < TT - 1);
    #pragma unroll 4
    for (int ci = 0; ci < H1; ++ci) {
        float v0 = tl ? ip[ci * TT - 1] : 0.f;
        float v1 = ip[ci * TT];
        float v2 = th ? ip[ci * TT + 1] : 0.f;
        a0 = fmaf(v0, wp[ci * 3 + 0], a0);
        a1 = fmaf(v1, wp[ci * 3 + 1], a1);
        a2 = fmaf(v2, wp[ci * 3 + 2], a2);
    }
    ((unsigned short*)(g_buf + OFF_PFT))[((size_t)b * 112 + t) * 256 + o] =
        f2bf(fmaxf(a0 + a1 + a2, 0.f));
}

// ---------- both 1x1 sigmoid heads ----------
__global__ void k_heads(const float* __restrict__ ws2, const float* __restrict__ bs2,
                        const float* __restrict__ we2, const float* __restrict__ be2,
                        float* __restrict__ out) {
    int which = blockIdx.x;
    const float* w  = which ? we2 : ws2;
    const float* bi = which ? be2 : bs2;
    int in_off = which ? OFF_EB : OFF_SB;
    int id = threadIdx.x;
    if (id >= BB * TT) return;
    int t = id % TT, b = id / TT;
    const float* ip = g_buf + in_off + b * H1 * TT + t;
    float acc = bi[0];
    for (int c = 0; c < H1; ++c) acc = fmaf(ip[c * TT], w[c], acc);
    out[40000 + which * 200 + id] = 1.f / (1.f + expf(-acc));
}

// ---------- w3b[n][o][c] bf16 from w3d[o][c][n] ----------
__global__ __launch_bounds__(256) void k_w3prep(const float* __restrict__ w3d) {
    __shared__ float tile[8192];
    int o = blockIdx.x, tid = threadIdx.x;
    const float* src = w3d + o * 8192;
    for (int idx = tid; idx < 8192; idx += 256) tile[idx] = src[idx];
    __syncthreads();
    int n = tid & 31, ch = tid >> 5;
    unsigned short* w3b = (unsigned short*)(g_buf + OFF_W3B);
    unsigned int w[16];
    #pragma unroll
    for (int c2 = 0; c2 < 16; ++c2) {
        int c = ch * 32 + c2 * 2;
        w[c2] = (unsigned int)f2bf(tile[c * 32 + n]) |
                ((unsigned int)f2bf(tile[(c + 1) * 32 + n]) << 16);
    }
    uint4* dst = (uint4*)(w3b + ((size_t)n * 512 + o) * 256 + ch * 32);
    dst[0] = make_uint4(w[0], w[1], w[2], w[3]);
    dst[1] = make_uint4(w[4], w[5], w[6], w[7]);
    dst[2] = make_uint4(w[8], w[9], w[10], w[11]);
    dst[3] = make_uint4(w[12], w[13], w[14], w[15]);
}

// ---------- ATb pair-words (MFMA), quarter-permuted layout ----------
// row m of (b,og): 4 quarters of 16B; quarter kq at pos (kq+m+(m>>2))&3;
// word (4B) for ch c16 = (A[m,c]/3, A[m+1,c]/3) bf16.
__global__ __launch_bounds__(256) void k_Am() {
    int mt = blockIdx.x, nt = blockIdx.y, bn = blockIdx.z;
    int b = bn >> 5, n = bn & 31;
    int wv = threadIdx.x >> 6, lane = threadIdx.x & 63;
    int r = lane & 15, g = lane >> 4;
    const unsigned short* ap = (const unsigned short*)(g_buf + OFF_PFT)
                               + ((size_t)b * 112 + mt * 16 + r) * 256 + g * 8;
    const unsigned short* bp = (const unsigned short*)(g_buf + OFF_W3B)
                               + ((size_t)n * 512 + nt * 128 + wv * 32 + r) * 256 + g * 8;
    f32x4 acc0 = {0.f, 0.f, 0.f, 0.f}, acc1 = {0.f, 0.f, 0.f, 0.f};
    #pragma unroll
    for (int ks = 0; ks < 8; ++ks) {
        bf16x8 a  = *(const bf16x8*)(ap + ks * 32);
        bf16x8 b0 = *(const bf16x8*)(bp + ks * 32);
        bf16x8 b1 = *(const bf16x8*)(bp + 16 * 256 + ks * 32);
        acc0 = __builtin_amdgcn_mfma_f32_16x16x32_bf16(a, b0, acc0, 0, 0, 0);
        acc1 = __builtin_amdgcn_mfma_f32_16x16x32_bf16(a, b1, acc1, 0, 0, 0);
    }
    unsigned short* ATb = (unsigned short*)(g_buf + OFF_ATB);
    float v0[4], v1[4];
    #pragma unroll
    for (int reg = 0; reg < 4; ++reg) {
        v0[reg] = acc0[reg] * (1.f / 3.f);
        v1[reg] = acc1[reg] * (1.f / 3.f);
    }
    float n0 = __shfl(v0[0], (lane + 16) & 63);
    float n1 = __shfl(v1[0], (lane + 16) & 63);
    int t0i = mt * 16 + g * 4;
    int o0 = nt * 128 + wv * 32 + r;
    #pragma unroll
    for (int s = 0; s < 2; ++s) {
        int o = s ? (o0 + 16) : o0;
        const float* v = s ? v1 : v0;
        float nx = s ? n1 : n0;
        int og = o >> 4, c16 = o & 15;
        int kq = c16 >> 2, wrd = c16 & 3;
        size_t gb = (size_t)(b * 32 + og) * 3200;
        #pragma unroll
        for (int reg = 0; reg < 4; ++reg) {
            int t = t0i + reg;
            if (t >= TT) continue;
            int m = n * 100 + t;
            size_t off = (gb + m) * 32 + (size_t)(((kq + m + (m >> 2)) & 3) * 8 + wrd * 2);
            if (reg < 3) {
                *(unsigned int*)(ATb + off) =
                    (unsigned int)f2bf(v[reg]) | ((unsigned int)f2bf(v[reg + 1]) << 16);
            } else if (t == TT - 1) {
                *(unsigned int*)(ATb + off) = (unsigned int)f2bf(v[3]);
            } else if (g < 3) {
                *(unsigned int*)(ATb + off) =
                    (unsigned int)f2bf(v[3]) | ((unsigned int)f2bf(nx) << 16);
            } else {
                ATb[off] = f2bf(v[3]);          // lo only; next block writes hi
            }
        }
        if (g == 0 && mt > 0) {                  // hi of previous block's last row
            int m = n * 100 + t0i - 1;
            size_t off = (gb + m) * 32 + (size_t)(((kq + m + (m >> 2)) & 3) * 8 + wrd * 2);
            ATb[off + 1] = f2bf(v[0]);
        }
    }
}

// ---------- BM gather v3: 16ch/block, reg-prefetch, wave OOB-skip ----------
__global__ __launch_bounds__(256) void k_bm2(const float* __restrict__ b3d) {
    __shared__ uint4 Ash[3200];                  // 800 rows x 64B = 51.2 KB
    int qt = blockIdx.x, og = blockIdx.y, b = blockIdx.z;
    int tid = threadIdx.x;
    int v = qt * 256 + tid;
    bool val = (v < NVALID);
    int vv = val ? v : 0;
    int i = (int)(100.5 - sqrt(10100.25 - 2.0 * (double)vv));
    if (i < 0) i = 0; if (i > 99) i = 99;
    while (100 * (i + 1) - ((i + 1) * i) / 2 <= vv && i < 99) ++i;
    while (100 * i - (i * (i - 1)) / 2 > vv && i > 0) --i;
    int j = i + (vv - (100 * i - (i * (i - 1)) / 2));
    int qv = i * 100 + j;
    const unsigned int* desc = (const unsigned int*)(g_buf + OFF_DESC);
    const uint4* src = (const uint4*)(g_buf + OFF_ATB) + (size_t)(b * 32 + og) * 12800;
    uint4 pf[13];
    #pragma unroll
    for (int p = 0; p < 13; ++p) {
        int ix = p * 256 + tid;
        pf[p] = src[ix < 3200 ? ix : 3199];
    }
    float acc[16];
    #pragma unroll
    for (int c = 0; c < 16; ++c) acc[c] = 0.f;

    for (int st = 0; st < 4; ++st) {
        __syncthreads();
        #pragma unroll
        for (int p = 0; p < 13; ++p) {
            int ix = p * 256 + tid;
            if (ix < 3200) Ash[ix] = pf[p];
        }
        if (st < 3) {
            const uint4* s2 = src + (st + 1) * 3200;
            #pragma unroll
            for (int p = 0; p < 13; ++p) {
                int ix = p * 256 + tid;
                pf[p] = s2[ix < 3200 ? ix : 3199];
            }
        }
        __syncthreads();
        for (int kk = 0; kk < 24; ++kk) {
            int k = st * 24 + kk;
            unsigned int d = desc[(size_t)k * 10240 + qv];
            unsigned int mode = (d >> 12) & 3u;
            if (__all(mode == 2u)) continue;
            int t12 = (int)(d & 0xFFFu);
            int ml = t12 - st * 800;
            int fm = (t12 + (t12 >> 2)) & 3;
            float dec = (float)(d >> 16) * (1.f / 65535.f);
            float w0 = (mode == 2u) ? 0.f : 1.f - dec;
            float w1 = (mode == 0u) ? dec : 0.f;
            unsigned int wpair;
            asm("v_cvt_pk_bf16_f32 %0, %1, %2" : "=v"(wpair) : "v"(w0), "v"(w1));
            int base = ml * 4;
            uint4 Q0 = Ash[base + (fm & 3)];
            uint4 Q1 = Ash[base + ((1 + fm) & 3)];
            uint4 Q2 = Ash[base + ((2 + fm) & 3)];
            uint4 Q3 = Ash[base + ((3 + fm) & 3)];
            dot2(acc[0],  Q0.x, wpair); dot2(acc[1],  Q0.y, wpair);
            dot2(acc[2],  Q0.z, wpair); dot2(acc[3],  Q0.w, wpair);
            dot2(acc[4],  Q1.x, wpair); dot2(acc[5],  Q1.y, wpair);
            dot2(acc[6],  Q1.z, wpair); dot2(acc[7],  Q1.w, wpair);
            dot2(acc[8],  Q2.x, wpair); dot2(acc[9],  Q2.y, wpair);
            dot2(acc[10], Q2.z, wpair); dot2(acc[11], Q2.w, wpair);
            dot2(acc[12], Q3.x, wpair); dot2(acc[13], Q3.y, wpair);
            dot2(acc[14], Q3.z, wpair); dot2(acc[15], Q3.w, wpair);
        }
    }
    if (val) {
        unsigned short* cm2T = (unsigned short*)(g_buf + OFF_CM2T);
        unsigned int w[8];
        #pragma unroll
        for (int c2 = 0; c2 < 8; ++c2) {
            float x0 = fmaxf(acc[c2 * 2]     + b3d[og * 16 + c2 * 2],     0.f);
            float x1 = fmaxf(acc[c2 * 2 + 1] + b3d[og * 16 + c2 * 2 + 1], 0.f);
            w[c2] = (unsigned int)f2bf(x0) | ((unsigned int)f2bf(x1) << 16);
        }
        uint4* dst = (uint4*)(cm2T + ((size_t)b * IJ + qv) * 512 + og * 16);
        dst[0] = make_uint4(w[0], w[1], w[2], w[3]);
        dst[1] = make_uint4(w[4], w[5], w[6], w[7]);
    }
}

// ---------- P1 fill for invalid (i>j) pixels: constant c_inv ----------
__global__ void k_q1f() {
    int id = blockIdx.x * 256 + threadIdx.x;    // 2*IJ*16
    if (id >= BB * IJ * 16) return;
    int c = id & 15;
    int q = (id >> 4) % IJ;
    int b = id / (16 * IJ);
    int i = q / 100, j = q - i * 100;
    if (i <= j) return;
    uint4 w = ((const uint4*)(g_buf + OFF_CINV))[c];
    unsigned short* P1 = (unsigned short*)(g_buf + OFF_P1) + (size_t)b * PSTRIDE;
    *(uint4*)(P1 + (size_t)((i + 1) * PADW + j + 1) * H2C + c * 8) = w;
}

#define MFMA16(a, b, c) __builtin_amdgcn_mfma_f32_16x16x32_bf16(a, b, c, 0, 0, 0)

// ---------- q1: valid pixels only, pipelined GEMM ----------
__global__ __launch_bounds__(256) void k_q1m(const float* __restrict__ bias) {
    __shared__ uint4 As[2048];
    __shared__ int qmap[32];
    const unsigned short* Acm = (const unsigned short*)(g_buf + OFF_CM2T);
    const unsigned short* Bw  = (const unsigned short*)(g_buf + OFF_WQ1B);
    unsigned short* P1 = (unsigned short*)(g_buf + OFF_P1);
    int m0 = blockIdx.x * 32, b = blockIdx.y;
    int tid = threadIdx.x;
    if (tid < 32) {
        int v = m0 + tid; if (v >= NVALID) v = NVALID - 1;
        int i = (int)(100.5 - sqrt(10100.25 - 2.0 * (double)v));
        if (i < 0) i = 0; if (i > 99) i = 99;
        while (100 * (i + 1) - ((i + 1) * i) / 2 <= v && i < 99) ++i;
        while (100 * i - (i * (i - 1)) / 2 > v && i > 0) --i;
        int j = i + (v - (100 * i - (i * (i - 1)) / 2));
        qmap[tid] = i * 100 + j;
    }
    __syncthreads();
    for (int idx = tid; idx < 2048; idx += 256) {
        int px = idx >> 6, ch = idx & 63;
        int ch2 = ch ^ (px & 7) ^ (((px >> 3) & 1) << 3);
        As[px * 64 + ch2] = *(const uint4*)(Acm + ((size_t)b * IJ + qmap[px]) * 512 + ch * 8);
    }
    __syncthreads();
    int wv = tid >> 6, lane = tid & 63, r = lane & 15, g = lane >> 4;
    int q0 = wv * 32;
    f32x4 acc[2][2] = {{{0.f,0.f,0.f,0.f},{0.f,0.f,0.f,0.f}},{{0.f,0.f,0.f,0.f},{0.f,0.f,0.f,0.f}}};
    bf16x8 Bb[4][2], Aa[2][2];
#define Q1_LB(slot, it_) { const unsigned short* bp = Bw + (size_t)(q0 + r) * 512 + (it_) * 32 + g * 8; \
    Bb[slot][0] = *(const bf16x8*)bp; Bb[slot][1] = *(const bf16x8*)(bp + 16 * 512); }
#define Q1_LA(slot, it_) { int ch = (it_) * 4 + g; \
    int px0 = r, px1 = 16 + r; \
    Aa[slot][0] = *(const bf16x8*)&As[px0 * 64 + (ch ^ (px0 & 7) ^ (((px0 >> 3) & 1) << 3))]; \
    Aa[slot][1] = *(const bf16x8*)&As[px1 * 64 + (ch ^ (px1 & 7) ^ (((px1 >> 3) & 1) << 3))]; }
    Q1_LB(0, 0); Q1_LB(1, 1); Q1_LB(2, 2); Q1_LA(0, 0);
    #pragma unroll
    for (int it = 0; it < 16; ++it) {
        if (it + 3 < 16) Q1_LB((it + 3) & 3, it + 3);
        if (it + 1 < 16) Q1_LA((it + 1) & 1, it + 1);
        int s = it & 3, sa = it & 1;
        acc[0][0] = MFMA16(Aa[sa][0], Bb[s][0], acc[0][0]);
        acc[0][1] = MFMA16(Aa[sa][0], Bb[s][1], acc[0][1]);
        acc[1][0] = MFMA16(Aa[sa][1], Bb[s][0], acc[1][0]);
        acc[1][1] = MFMA16(Aa[sa][1], Bb[s][1], acc[1][1]);
    }
    float bi0 = bias[q0 + r], bi1 = bias[q0 + 16 + r];
    unsigned short* Pout = P1 + (size_t)b * PSTRIDE;
    #pragma unroll
    for (int mt = 0; mt < 2; ++mt)
        #pragma unroll
        for (int reg = 0; reg < 4; ++reg) {
            int px = mt * 16 + g * 4 + reg;
            if (m0 + px < NVALID) {
                int q = qmap[px];
                int i = q / 100, j = q - i * 100;
                size_t base = (size_t)((i + 1) * PADW + j + 1) * H2C;
                Pout[base + q0 + r]      = f2bf(fmaxf(acc[mt][0][reg] + bi0, 0.f));
                Pout[base + q0 + 16 + r] = f2bf(fmaxf(acc[mt][1][reg] + bi1, 0.f));
            }
        }
}

// ---------- 3x3 conv 128->128, pipelined; FQ4: fuse 1x1->2 + sigmoid ----------
template<int FQ4>
__global__ __launch_bounds__(256) void k_c3m(int in_off, int w_off,
                                             const float* __restrict__ bias,
                                             int out_off,
                                             const float* __restrict__ wq4,
                                             const float* __restrict__ bq4,
                                             float* __restrict__ out) {
    __shared__ uint4 As[1632];
    const unsigned short* Pin = (const unsigned short*)(g_buf + in_off);
    const unsigned short* wB  = (const unsigned short*)(g_buf + w_off);
    int jt = blockIdx.x, i = blockIdx.y, b = blockIdx.z;
    int j0 = (jt == 3) ? 68 : jt * 32;
    int tid = threadIdx.x;
    const unsigned short* Ab = Pin + (size_t)b * PSTRIDE;
    for (int idx = tid; idx < 1632; idx += 256) {
        int ky = idx / 544, rem = idx - ky * 544;
        int px = rem >> 4, ch = rem & 15;
        int ch2 = ch ^ (px & 7) ^ (((px >> 3) & 1) << 3);
        As[(ky * 34 + px) * 16 + ch2] =
            *(const uint4*)(Ab + (size_t)((i + ky) * PADW + j0 + px) * H2C + ch * 8);
    }
    __syncthreads();
    int wv = tid >> 6, lane = tid & 63, r = lane & 15, g = lane >> 4;
    int q0 = wv * 32;
    f32x4 acc[2][2] = {{{0.f,0.f,0.f,0.f},{0.f,0.f,0.f,0.f}},{{0.f,0.f,0.f,0.f},{0.f,0.f,0.f,0.f}}};
    bf16x8 Bb[4][2], Aa[2][2];
#define C3_LB(slot, it_) { int tap = (it_) >> 2, cc = (it_) & 3; \
    const unsigned short* bp = wB + (size_t)(q0 + r) * 1152 + tap * 128 + cc * 32 + g * 8; \
    Bb[slot][0] = *(const bf16x8*)bp; Bb[slot][1] = *(const bf16x8*)(bp + 16 * 1152); }
#define C3_LA(slot, it_) { int tap = (it_) >> 2, cc = (it_) & 3; \
    int ky = tap / 3, kx = tap - ky * 3; int ch = cc * 4 + g; \
    int px0 = r + kx, px1 = 16 + r + kx; \
    Aa[slot][0] = *(const bf16x8*)&As[(ky * 34 + px0) * 16 + (ch ^ (px0 & 7) ^ (((px0 >> 3) & 1) << 3))]; \
    Aa[slot][1] = *(const bf16x8*)&As[(ky * 34 + px1) * 16 + (ch ^ (px1 & 7) ^ (((px1 >> 3) & 1) << 3))]; }
    C3_LB(0, 0); C3_LB(1, 1); C3_LB(2, 2); C3_LA(0, 0);
    #pragma unroll
    for (int it = 0; it < 36; ++it) {
        if (it + 3 < 36) C3_LB((it + 3) & 3, it + 3);
        if (it + 1 < 36) C3_LA((it + 1) & 1, it + 1);
        int s = it & 3, sa = it & 1;
        acc[0][0] = MFMA16(Aa[sa][0], Bb[s][0], acc[0][0]);
        acc[0][1] = MFMA16(Aa[sa][0], Bb[s][1], acc[0][1]);
        acc[1][0] = MFMA16(Aa[sa][1], Bb[s][0], acc[1][0]);
        acc[1][1] = MFMA16(Aa[sa][1], Bb[s][1], acc[1][1]);
    }
    float bi0 = bias[q0 + r], bi1 = bias[q0 + 16 + r];
    if constexpr (!FQ4) {
        unsigned short* Ob = (unsigned short*)(g_buf + out_off) + (size_t)b * PSTRIDE;
        #pragma unroll
        for (int mt = 0; mt < 2; ++mt)
            #pragma unroll
            for (int reg = 0; reg < 4; ++reg) {
                int j = j0 + mt * 16 + g * 4 + reg;
                size_t base = (size_t)((i + 1) * PADW + j + 1) * H2C;
                Ob[base + q0 + r]      = f2bf(fmaxf(acc[mt][0][reg] + bi0, 0.f));
                Ob[base + q0 + 16 + r] = f2bf(fmaxf(acc[mt][1][reg] + bi1, 0.f));
            }
    } else {
        __shared__ float part[4][2][32];
        float w40a = wq4[q0 + r],       w40b = wq4[q0 + 16 + r];
        float w41a = wq4[128 + q0 + r], w41b = wq4[128 + q0 + 16 + r];
        #pragma unroll
        for (int mt = 0; mt < 2; ++mt)
            #pragma unroll
            for (int reg = 0; reg < 4; ++reg) {
                float x0 = fmaxf(acc[mt][0][reg] + bi0, 0.f);
                float x1 = fmaxf(acc[mt][1][reg] + bi1, 0.f);
                float p0 = x0 * w40a + x1 * w40b;
                float p1 = x0 * w41a + x1 * w41b;
                #pragma unroll
                for (int off = 1; off < 16; off <<= 1) {
                    p0 += __shfl_xor(p0, off);
                    p1 += __shfl_xor(p1, off);
                }
                if (r == 0) {
                    int px = mt * 16 + g * 4 + reg;
                    part[wv][0][px] = p0;
                    part[wv][1][px] = p1;
                }
            }
        __syncthreads();
        if (tid < 64) {
            int px = tid & 31, hd = tid >> 5;
            float s = part[0][hd][px] + part[1][hd][px] + part[2][hd][px] + part[3][hd][px]
                      + bq4[hd];
            out[(size_t)(b * 2 + hd) * IJ + i * 100 + (j0 + px)] = 1.f / (1.f + expf(-s));
        }
    }
}

extern "C" void kernel_launch(void* const* d_in, const int* in_sizes, int n_in,
                              void* d_out, int out_size, void* d_ws, size_t ws_size,
                              hipStream_t stream) {
    const float* x   = (const float*)d_in[0];
    const float* wb1 = (const float*)d_in[1];  const float* bb1 = (const float*)d_in[2];
    const float* wb2 = (const float*)d_in[3];  const float* bb2 = (const float*)d_in[4];
    const float* ws1 = (const float*)d_in[5];  const float* bs1 = (const float*)d_in[6];
    const float* ws2 = (const float*)d_in[7];  const float* bs2 = (const float*)d_in[8];
    const float* we1 = (const float*)d_in[9];  const float* be1 = (const float*)d_in[10];
    const float* we2 = (const float*)d_in[11]; const float* be2 = (const float*)d_in[12];
    const float* wp  = (const float*)d_in[13]; const float* bp  = (const float*)d_in[14];
    const float* w3d = (const float*)d_in[15]; const float* b3d = (const float*)d_in[16];
    const float* wq1 = (const float*)d_in[17]; const float* bq1 = (const float*)d_in[18];
    const float* wq2 = (const float*)d_in[19]; const float* bq2 = (const float*)d_in[20];
    const float* wq3 = (const float*)d_in[21]; const float* bq3 = (const float*)d_in[22];
    const float* wq4 = (const float*)d_in[23]; const float* bq4 = (const float*)d_in[24];
    float* out = (float*)d_out;

    k_prep<<<PREP_IDS / 256, 256, 0, stream>>>(wq1, wq2, wq3, x, b3d, bq1);
    k_w3prep<<<512, 256, 0, stream>>>(w3d);
    k_q1f<<<(BB * IJ * 16 + 255) / 256, 256, 0, stream>>>();
    k_conv_t<100, 64, 400><<<200, 256, 0, stream>>>(OFF_XT, wb1, bb1, OFF_H1);
    k_conv_t<64, 64, 256><<<200, 256, 0, stream>>>(OFF_H1, wb2, bb2, OFF_H2);
    k_conv_se<<<400, 256, 0, stream>>>(ws1, bs1, we1, be1);
    k_heads<<<2, 256, 0, stream>>>(ws2, bs2, we2, be2, out);
    k_conv_pf<<<200, 256, 0, stream>>>(wp, bp);
    k_Am<<<dim3(7, 4, 64), 256, 0, stream>>>();
    k_bm2<<<dim3(20, 32, 2), 256, 0, stream>>>(b3d);
    k_q1m<<<dim3((NVALID + 31) / 32, 2), 256, 0, stream>>>(bq1);
    k_c3m<0><<<dim3(4, 100, 2), 256, 0, stream>>>(OFF_P1, OFF_WQ2B, bq2, OFF_P2,
                                                  nullptr, nullptr, nullptr);
    k_c3m<1><<<dim3(4, 100, 2), 256, 0, stream>>>(OFF_P2, OFF_WQ3B, bq3, 0,
                                                  wq4, bq4, out);
}

// Round 10
// 303.594 us; speedup vs baseline: 1.1995x; 1.1995x over previous
//
#include <hip/hip_runtime.h>
#include <hip/hip_bf16.h>
#include <math.h>

#define TT  100
#define CIN 400
#define H1  256
#define NS  32
#define NP  96
#define H3  512
#define H2C 128
#define BB  2
#define IJ  10000
#define NVALID 5050
#define PADW 102
#define PPIX 10432
#define PSTRIDE (PPIX * H2C)

typedef __attribute__((ext_vector_type(8))) short bf16x8;
typedef __attribute__((ext_vector_type(4))) float f32x4;

// ---- static scratch (float units) ----
#define OFF_XT   0
#define OFF_H1   80000
#define OFF_H2   131200
#define OFF_SB   182400
#define OFF_EB   233600
#define OFF_PF   284800
#define OFF_ATB  336000      // bf16 pairs ATb2[b][64][3200][8][2]
#define OFF_CM2T 3612800     // bf16 [b][ij][512] (valid rows only)
#define OFF_P1   8732800
#define OFF_P2   10068096
#define OFF_CINV 11403392    // uint[64]: c_inv as bf16 pairs
#define OFF_WQ1B 12683392
#define OFF_WQ2B 12716160
#define OFF_WQ3B 12789888
#define OFF_DESC 12863616    // u32 [96][10240]
#define OFF_PFT  13846656    // bf16 [b][112][256]
#define OFF_W3B  13875328    // bf16 [n][o][c]
#define G_TOTAL  15972480

__device__ __align__(16) float g_buf[G_TOTAL];

__device__ inline unsigned short f2bf(float f) {
    __hip_bfloat16 h = __float2bfloat16(f);
    return *(unsigned short*)&h;
}
__device__ inline float bf2f(unsigned short u) {
    union { unsigned int i; float f; } v; v.i = ((unsigned int)u) << 16; return v.f;
}
__device__ inline void dot2(float& acc, unsigned int a, unsigned int w) {
    asm("v_dot2_f32_bf16 %0, %1, %2, %0" : "+v"(acc) : "v"(a), "v"(w));
}

// ---------- merged prep ----------
__global__ void k_prep(const float* __restrict__ wq1, const float* __restrict__ wq2,
                       const float* __restrict__ wq3, const float* __restrict__ x,
                       const float* __restrict__ b3d, const float* __restrict__ bq1) {
    int id = blockIdx.x * 256 + threadIdx.x;
    if (id < 65536) {
        ((unsigned short*)(g_buf + OFF_WQ1B))[id] = f2bf(wq1[id]);
        return;
    }
    id -= 65536;
    if (id < 147456) {
        int q = id / 1152, k = id % 1152, tap = k >> 7, c = k & 127;
        ((unsigned short*)(g_buf + OFF_WQ2B))[id] = f2bf(wq2[(q * 128 + c) * 9 + tap]);
        return;
    }
    id -= 147456;
    if (id < 147456) {
        int q = id / 1152, k = id % 1152, tap = k >> 7, c = k & 127;
        ((unsigned short*)(g_buf + OFF_WQ3B))[id] = f2bf(wq3[(q * 128 + c) * 9 + tap]);
        return;
    }
    id -= 147456;
    if (id < 51712) {   // halo zero
        int c = id & 31;
        int h = (id >> 5) % 404;
        int bb = ((id >> 5) / 404) & 1;
        int buf = id / 25856;
        int pix;
        if (h < 102) pix = h;
        else if (h < 204) pix = 101 * PADW + (h - 102);
        else { int q = h - 204; pix = (1 + (q >> 1)) * PADW + ((q & 1) ? 101 : 0); }
        unsigned short* P = (unsigned short*)(g_buf + (buf ? OFF_P2 : OFF_P1))
                            + (size_t)bb * PSTRIDE + (size_t)pix * H2C;
        ((uint2*)P)[c] = make_uint2(0u, 0u);
        return;
    }
    id -= 51712;
    if (id < NP * 10240) {   // desc
        int k = id / 10240, q = id - k * 10240;
        int i = q / 100, j = q - i * 100;
        unsigned int nb = (unsigned int)((k / 3) * 100);
        unsigned int d;
        if (q >= IJ || i > j) {
            d = nb | (2u << 12);
        } else {
            double len = (double)(j - i + 2);
            double xmn = (double)i - 0.5 * len;
            double xmx = (double)(j + 1) + 0.5 * len;
            double plen = (xmx - xmn) / 95.0;
            double s = __dadd_rn(xmn, __dmul_rn(plen, (double)k));
            double tr = trunc(s);
            double dec = s - tr;
            int dn = (int)tr;
            int up = (int)ceil(s);
            bool okd = (unsigned)dn < (unsigned)TT;
            bool oku = (unsigned)up < (unsigned)TT;
            if (!okd) d = nb | (2u << 12);
            else if (oku && up == dn + 1) {
                unsigned int dfx = (unsigned int)__double2int_rn(dec * 65535.0);
                d = (nb + dn) | (dfx << 16);
            } else if (oku) {
                d = (nb + dn) | (1u << 12);
            } else {
                unsigned int dfx = (unsigned int)__double2int_rn(dec * 65535.0);
                d = (nb + dn) | (1u << 12) | (dfx << 16);
            }
        }
        ((unsigned int*)(g_buf + OFF_DESC))[id] = d;
        return;
    }
    id -= NP * 10240;
    if (id < BB * TT * CIN) {   // x transpose
        int c = id % CIN, t = (id / CIN) % TT, b = id / (CIN * TT);
        g_buf[OFF_XT + (b * CIN + c) * TT + t] = x[id];
        return;
    }
    id -= BB * TT * CIN;
    if (id < BB * 12 * 256) {   // zero pfT pad rows
        int c = id & 255, tp = (id >> 8) % 12, b = id / (12 * 256);
        ((unsigned short*)(g_buf + OFF_PFT))[((size_t)b * 112 + 100 + tp) * 256 + c] = 0;
        return;
    }
    id -= BB * 12 * 256;
    if (id < 128) {   // c_inv[q] = relu(wq1 . relu(b3d) + bq1), packed bf16 pairs
        int q = id;
        float acc = bq1[q];
        const float* wr = wq1 + q * 512;
        #pragma unroll 8
        for (int c = 0; c < 512; ++c) acc = fmaf(wr[c], fmaxf(b3d[c], 0.f), acc);
        acc = fmaxf(acc, 0.f);
        float accO = __shfl_xor(acc, 1);
        if ((id & 1) == 0)
            ((unsigned int*)(g_buf + OFF_CINV))[id >> 1] =
                (unsigned int)f2bf(acc) | ((unsigned int)f2bf(accO) << 16);
    }
}
#define PREP_IDS (65536 + 147456 + 147456 + 51712 + NP * 10240 + BB * TT * CIN + BB * 12 * 256 + 128)

// ---------- conv1d k=3 pad=1 + relu (3 acc chains) ----------
template<int IPG, int OPG, int CINTOT>
__global__ void k_conv_t(int in_off, const float* __restrict__ w,
                         const float* __restrict__ bias, int out_off) {
    int id = blockIdx.x * 256 + threadIdx.x;
    if (id >= BB * H1 * TT) return;
    int t = id % TT, o = (id / TT) % H1, b = id / (TT * H1);
    const float* ip = g_buf + in_off + (b * CINTOT + (o / OPG) * IPG) * TT + t;
    const float* wp = w + o * IPG * 3;
    float a0 = bias[o], a1 = 0.f, a2 = 0.f;
    bool t0 = (t > 0), t1 = (t < TT - 1);
    #pragma unroll 4
    for (int ci = 0; ci < IPG; ++ci) {
        float v0 = t0 ? ip[ci * TT - 1] : 0.f;
        float v1 = ip[ci * TT];
        float v2 = t1 ? ip[ci * TT + 1] : 0.f;
        a0 = fmaf(v0, wp[ci * 3 + 0], a0);
        a1 = fmaf(v1, wp[ci * 3 + 1], a1);
        a2 = fmaf(v2, wp[ci * 3 + 2], a2);
    }
    g_buf[out_off + id] = fmaxf(a0 + a1 + a2, 0.f);
}

// ---------- s & e convs merged ----------
__global__ void k_conv_se(const float* __restrict__ ws1, const float* __restrict__ bs1,
                          const float* __restrict__ we1, const float* __restrict__ be1) {
    int sec = blockIdx.x >= 200;
    int id = (blockIdx.x - sec * 200) * 256 + threadIdx.x;
    if (id >= BB * H1 * TT) return;
    const float* w  = sec ? we1 : ws1;
    const float* bi = sec ? be1 : bs1;
    int out_off = sec ? OFF_EB : OFF_SB;
    int t = id % TT, o = (id / TT) % H1, b = id / (TT * H1);
    const float* ip = g_buf + OFF_H2 + (b * H1 + (o / 64) * 64) * TT + t;
    const float* wp = w + o * 64 * 3;
    float a0 = bi[o], a1 = 0.f, a2 = 0.f;
    bool tl = (t > 0), th = (t < TT - 1);
    #pragma unroll 4
    for (int ci = 0; ci < 64; ++ci) {
        float v0 = tl ? ip[ci * TT - 1] : 0.f;
        float v1 = ip[ci * TT];
        float v2 = th ? ip[ci * TT + 1] : 0.f;
        a0 = fmaf(v0, wp[ci * 3 + 0], a0);
        a1 = fmaf(v1, wp[ci * 3 + 1], a1);
        a2 = fmaf(v2, wp[ci * 3 + 2], a2);
    }
    g_buf[out_off + id] = fmaxf(a0 + a1 + a2, 0.f);
}

// ---------- pf conv writing pfT bf16 directly ----------
__global__ void k_conv_pf(const float* __restrict__ w, const float* __restrict__ bias) {
    int id = blockIdx.x * 256 + threadIdx.x;
    if (id >= BB * H1 * TT) return;
    int t = id % TT, o = (id / TT) % H1, b = id / (TT * H1);
    const float* ip = g_buf + OFF_H2 + (b * H1) * TT + t;
    const float* wp = w + o * H1 * 3;
    float a0 = bias[o], a1 = 0.f, a2 = 0.f;
    bool tl = (t > 0), th = (t < TT - 1);
    #pragma unroll 4
    for (int ci = 0; ci < H1; ++ci) {
        float v0 = tl ? ip[ci * TT - 1] : 0.f;
        float v1 = ip[ci * TT];
        float v2 = th ? ip[ci * TT + 1] : 0.f;
        a0 = fmaf(v0, wp[ci * 3 + 0], a0);
        a1 = fmaf(v1, wp[ci * 3 + 1], a1);
        a2 = fmaf(v2, wp[ci * 3 + 2], a2);
    }
    ((unsigned short*)(g_buf + OFF_PFT))[((size_t)b * 112 + t) * 256 + o] =
        f2bf(fmaxf(a0 + a1 + a2, 0.f));
}

// ---------- both 1x1 sigmoid heads ----------
__global__ void k_heads(const float* __restrict__ ws2, const float* __restrict__ bs2,
                        const float* __restrict__ we2, const float* __restrict__ be2,
                        float* __restrict__ out) {
    int which = blockIdx.x;
    const float* w  = which ? we2 : ws2;
    const float* bi = which ? be2 : bs2;
    int in_off = which ? OFF_EB : OFF_SB;
    int id = threadIdx.x;
    if (id >= BB * TT) return;
    int t = id % TT, b = id / TT;
    const float* ip = g_buf + in_off + b * H1 * TT + t;
    float acc = bi[0];
    for (int c = 0; c < H1; ++c) acc = fmaf(ip[c * TT], w[c], acc);
    out[40000 + which * 200 + id] = 1.f / (1.f + expf(-acc));
}

// ---------- w3b[n][o][c] bf16 from w3d[o][c][n] ----------
__global__ __launch_bounds__(256) void k_w3prep(const float* __restrict__ w3d) {
    __shared__ float tile[8192];
    int o = blockIdx.x, tid = threadIdx.x;
    const float* src = w3d + o * 8192;
    for (int idx = tid; idx < 8192; idx += 256) tile[idx] = src[idx];
    __syncthreads();
    int n = tid & 31, ch = tid >> 5;
    unsigned short* w3b = (unsigned short*)(g_buf + OFF_W3B);
    unsigned int w[16];
    #pragma unroll
    for (int c2 = 0; c2 < 16; ++c2) {
        int c = ch * 32 + c2 * 2;
        w[c2] = (unsigned int)f2bf(tile[c * 32 + n]) |
                ((unsigned int)f2bf(tile[(c + 1) * 32 + n]) << 16);
    }
    uint4* dst = (uint4*)(w3b + ((size_t)n * 512 + o) * 256 + ch * 32);
    dst[0] = make_uint4(w[0], w[1], w[2], w[3]);
    dst[1] = make_uint4(w[4], w[5], w[6], w[7]);
    dst[2] = make_uint4(w[8], w[9], w[10], w[11]);
    dst[3] = make_uint4(w[12], w[13], w[14], w[15]);
}

// ---------- ATb2 pairs: [b][o>>3][m][o&7][2] = ((1/3)A[m], (1/3)A[m+1]) bf16 ----------
__global__ __launch_bounds__(256) void k_Am() {
    int mt = blockIdx.x, nt = blockIdx.y, bn = blockIdx.z;
    int b = bn >> 5, n = bn & 31;
    int wv = threadIdx.x >> 6, lane = threadIdx.x & 63;
    int r = lane & 15, g = lane >> 4;
    const unsigned short* ap = (const unsigned short*)(g_buf + OFF_PFT)
                               + ((size_t)b * 112 + mt * 16 + r) * 256 + g * 8;
    const unsigned short* bp = (const unsigned short*)(g_buf + OFF_W3B)
                               + ((size_t)n * 512 + nt * 128 + wv * 32 + r) * 256 + g * 8;
    f32x4 acc0 = {0.f, 0.f, 0.f, 0.f}, acc1 = {0.f, 0.f, 0.f, 0.f};
    #pragma unroll
    for (int ks = 0; ks < 8; ++ks) {
        bf16x8 a  = *(const bf16x8*)(ap + ks * 32);
        bf16x8 b0 = *(const bf16x8*)(bp + ks * 32);
        bf16x8 b1 = *(const bf16x8*)(bp + 16 * 256 + ks * 32);
        acc0 = __builtin_amdgcn_mfma_f32_16x16x32_bf16(a, b0, acc0, 0, 0, 0);
        acc1 = __builtin_amdgcn_mfma_f32_16x16x32_bf16(a, b1, acc1, 0, 0, 0);
    }
    unsigned short* ATb = (unsigned short*)(g_buf + OFF_ATB);
    int o0 = nt * 128 + wv * 32 + r, o1 = o0 + 16;
    #pragma unroll
    for (int reg = 0; reg < 4; ++reg) {
        int t = mt * 16 + g * 4 + reg;
        if (t < TT) {
            size_t m = (size_t)(n * 100 + t);
            unsigned short v0 = f2bf(acc0[reg] * (1.f / 3.f));
            unsigned short v1 = f2bf(acc1[reg] * (1.f / 3.f));
            size_t base0 = ((size_t)(b * 64 + (o0 >> 3)) * 3200 + m) * 16 + (o0 & 7) * 2;
            size_t base1 = ((size_t)(b * 64 + (o1 >> 3)) * 3200 + m) * 16 + (o1 & 7) * 2;
            ATb[base0] = v0;
            ATb[base1] = v1;
            if (t > 0) {
                ATb[base0 - 16 + 1] = v0;
                ATb[base1 - 16 + 1] = v1;
            }
            if (t == TT - 1) {
                ATb[base0 + 1] = 0;
                ATb[base1 + 1] = 0;
            }
        }
    }
}

// ---------- BM gather (restored 74us version + wave OOB-skip) ----------
__global__ __launch_bounds__(256) void k_bm2(const float* __restrict__ b3d) {
    __shared__ uint4 Ash[1600];                 // 25.6 KB; slot = u ^ ((u>>3)&7)
    int qt = blockIdx.x, og = blockIdx.y, b = blockIdx.z;
    int tid = threadIdx.x;
    const unsigned int* desc = (const unsigned int*)(g_buf + OFF_DESC);
    const uint4* src = (const uint4*)((const unsigned short*)(g_buf + OFF_ATB)
                                      + (size_t)(b * 64 + og) * 3200 * 16);
    int q[2]; bool val[2];
    #pragma unroll
    for (int u = 0; u < 2; ++u) {
        int v = qt * 512 + u * 256 + tid;
        val[u] = (v < NVALID);
        int vv = val[u] ? v : 0;
        int i = (int)(100.5 - sqrt(10100.25 - 2.0 * (double)vv));
        if (i < 0) i = 0; if (i > 99) i = 99;
        while (100 * (i + 1) - ((i + 1) * i) / 2 <= vv && i < 99) ++i;
        while (100 * i - (i * (i - 1)) / 2 > vv && i > 0) --i;
        int j = i + (vv - (100 * i - (i * (i - 1)) / 2));
        q[u] = i * 100 + j;
    }
    float acc[2][8];
    #pragma unroll
    for (int u = 0; u < 2; ++u)
        #pragma unroll
        for (int c = 0; c < 8; ++c) acc[u][c] = 0.f;

    for (int st = 0; st < 4; ++st) {
        __syncthreads();
        for (int idx = tid; idx < 1600; idx += 256)
            Ash[idx ^ ((idx >> 3) & 7)] = src[st * 1600 + idx];
        __syncthreads();
        for (int kk = 0; kk < 24; ++kk) {
            const unsigned int* dk = desc + (size_t)(st * 24 + kk) * 10240;
            #pragma unroll
            for (int u = 0; u < 2; ++u) {
                unsigned int d = dk[q[u]];
                unsigned int mode = (d >> 12) & 3u;
                if (__all(mode == 2u)) continue;
                int t = (int)(d & 0xFFFu) - st * 800;
                float dec = (float)(d >> 16) * (1.f / 65535.f);
                float w0 = (mode == 2u) ? 0.f : 1.f - dec;
                float w1 = (mode == 0u) ? dec : 0.f;
                unsigned int wpair;
                asm("v_cvt_pk_bf16_f32 %0, %1, %2" : "=v"(wpair) : "v"(w0), "v"(w1));
                int u0 = t * 2;
                int s0 = u0 ^ ((u0 >> 3) & 7);
                uint4 A0 = Ash[s0];
                uint4 A1 = Ash[s0 ^ 1];
                dot2(acc[u][0], A0.x, wpair); dot2(acc[u][1], A0.y, wpair);
                dot2(acc[u][2], A0.z, wpair); dot2(acc[u][3], A0.w, wpair);
                dot2(acc[u][4], A1.x, wpair); dot2(acc[u][5], A1.y, wpair);
                dot2(acc[u][6], A1.z, wpair); dot2(acc[u][7], A1.w, wpair);
            }
        }
    }
    unsigned short* cm2T = (unsigned short*)(g_buf + OFF_CM2T);
    #pragma unroll
    for (int u = 0; u < 2; ++u) {
        if (val[u]) {
            unsigned int w[4];
            #pragma unroll
            for (int c2 = 0; c2 < 4; ++c2) {
                float v0 = fmaxf(acc[u][c2 * 2]     + b3d[og * 8 + c2 * 2],     0.f);
                float v1 = fmaxf(acc[u][c2 * 2 + 1] + b3d[og * 8 + c2 * 2 + 1], 0.f);
                w[c2] = (unsigned int)f2bf(v0) | ((unsigned int)f2bf(v1) << 16);
            }
            *(uint4*)(cm2T + ((size_t)b * IJ + q[u]) * 512 + og * 8) =
                make_uint4(w[0], w[1], w[2], w[3]);
        }
    }
}

// ---------- P1 fill for invalid (i>j) pixels: constant c_inv ----------
__global__ void k_q1f() {
    int id = blockIdx.x * 256 + threadIdx.x;    // 2*IJ*16
    if (id >= BB * IJ * 16) return;
    int c = id & 15;
    int q = (id >> 4) % IJ;
    int b = id / (16 * IJ);
    int i = q / 100, j = q - i * 100;
    if (i <= j) return;
    uint4 w = ((const uint4*)(g_buf + OFF_CINV))[c];
    unsigned short* P1 = (unsigned short*)(g_buf + OFF_P1) + (size_t)b * PSTRIDE;
    *(uint4*)(P1 + (size_t)((i + 1) * PADW + j + 1) * H2C + c * 8) = w;
}

#define MFMA16(a, b, c) __builtin_amdgcn_mfma_f32_16x16x32_bf16(a, b, c, 0, 0, 0)

// ---------- q1: valid pixels only, pipelined GEMM ----------
__global__ __launch_bounds__(256) void k_q1m(const float* __restrict__ bias) {
    __shared__ uint4 As[2048];
    __shared__ int qmap[32];
    const unsigned short* Acm = (const unsigned short*)(g_buf + OFF_CM2T);
    const unsigned short* Bw  = (const unsigned short*)(g_buf + OFF_WQ1B);
    unsigned short* P1 = (unsigned short*)(g_buf + OFF_P1);
    int m0 = blockIdx.x * 32, b = blockIdx.y;
    int tid = threadIdx.x;
    if (tid < 32) {
        int v = m0 + tid; if (v >= NVALID) v = NVALID - 1;
        int i = (int)(100.5 - sqrt(10100.25 - 2.0 * (double)v));
        if (i < 0) i = 0; if (i > 99) i = 99;
        while (100 * (i + 1) - ((i + 1) * i) / 2 <= v && i < 99) ++i;
        while (100 * i - (i * (i - 1)) / 2 > v && i > 0) --i;
        int j = i + (v - (100 * i - (i * (i - 1)) / 2));
        qmap[tid] = i * 100 + j;
    }
    __syncthreads();
    for (int idx = tid; idx < 2048; idx += 256) {
        int px = idx >> 6, ch = idx & 63;
        int ch2 = ch ^ (px & 7) ^ (((px >> 3) & 1) << 3);
        As[px * 64 + ch2] = *(const uint4*)(Acm + ((size_t)b * IJ + qmap[px]) * 512 + ch * 8);
    }
    __syncthreads();
    int wv = tid >> 6, lane = tid & 63, r = lane & 15, g = lane >> 4;
    int q0 = wv * 32;
    f32x4 acc[2][2] = {{{0.f,0.f,0.f,0.f},{0.f,0.f,0.f,0.f}},{{0.f,0.f,0.f,0.f},{0.f,0.f,0.f,0.f}}};
    bf16x8 Bb[4][2], Aa[2][2];
#define Q1_LB(slot, it_) { const unsigned short* bp = Bw + (size_t)(q0 + r) * 512 + (it_) * 32 + g * 8; \
    Bb[slot][0] = *(const bf16x8*)bp; Bb[slot][1] = *(const bf16x8*)(bp + 16 * 512); }
#define Q1_LA(slot, it_) { int ch = (it_) * 4 + g; \
    int px0 = r, px1 = 16 + r; \
    Aa[slot][0] = *(const bf16x8*)&As[px0 * 64 + (ch ^ (px0 & 7) ^ (((px0 >> 3) & 1) << 3))]; \
    Aa[slot][1] = *(const bf16x8*)&As[px1 * 64 + (ch ^ (px1 & 7) ^ (((px1 >> 3) & 1) << 3))]; }
    Q1_LB(0, 0); Q1_LB(1, 1); Q1_LB(2, 2); Q1_LA(0, 0);
    #pragma unroll
    for (int it = 0; it < 16; ++it) {
        if (it + 3 < 16) Q1_LB((it + 3) & 3, it + 3);
        if (it + 1 < 16) Q1_LA((it + 1) & 1, it + 1);
        int s = it & 3, sa = it & 1;
        acc[0][0] = MFMA16(Aa[sa][0], Bb[s][0], acc[0][0]);
        acc[0][1] = MFMA16(Aa[sa][0], Bb[s][1], acc[0][1]);
        acc[1][0] = MFMA16(Aa[sa][1], Bb[s][0], acc[1][0]);
        acc[1][1] = MFMA16(Aa[sa][1], Bb[s][1], acc[1][1]);
    }
    float bi0 = bias[q0 + r], bi1 = bias[q0 + 16 + r];
    unsigned short* Pout = P1 + (size_t)b * PSTRIDE;
    #pragma unroll
    for (int mt = 0; mt < 2; ++mt)
        #pragma unroll
        for (int reg = 0; reg < 4; ++reg) {
            int px = mt * 16 + g * 4 + reg;
            if (m0 + px < NVALID) {
                int q = qmap[px];
                int i = q / 100, j = q - i * 100;
                size_t base = (size_t)((i + 1) * PADW + j + 1) * H2C;
                Pout[base + q0 + r]      = f2bf(fmaxf(acc[mt][0][reg] + bi0, 0.f));
                Pout[base + q0 + 16 + r] = f2bf(fmaxf(acc[mt][1][reg] + bi1, 0.f));
            }
        }
}

// ---------- 3x3 conv 128->128, pipelined; FQ4: fuse 1x1->2 + sigmoid ----------
template<int FQ4>
__global__ __launch_bounds__(256) void k_c3m(int in_off, int w_off,
                                             const float* __restrict__ bias,
                                             int out_off,
                                             const float* __restrict__ wq4,
                                             const float* __restrict__ bq4,
                                             float* __restrict__ out) {
    __shared__ uint4 As[1632];
    const unsigned short* Pin = (const unsigned short*)(g_buf + in_off);
    const unsigned short* wB  = (const unsigned short*)(g_buf + w_off);
    int jt = blockIdx.x, i = blockIdx.y, b = blockIdx.z;
    int j0 = (jt == 3) ? 68 : jt * 32;
    int tid = threadIdx.x;
    const unsigned short* Ab = Pin + (size_t)b * PSTRIDE;
    for (int idx = tid; idx < 1632; idx += 256) {
        int ky = idx / 544, rem = idx - ky * 544;
        int px = rem >> 4, ch = rem & 15;
        int ch2 = ch ^ (px & 7) ^ (((px >> 3) & 1) << 3);
        As[(ky * 34 + px) * 16 + ch2] =
            *(const uint4*)(Ab + (size_t)((i + ky) * PADW + j0 + px) * H2C + ch * 8);
    }
    __syncthreads();
    int wv = tid >> 6, lane = tid & 63, r = lane & 15, g = lane >> 4;
    int q0 = wv * 32;
    f32x4 acc[2][2] = {{{0.f,0.f,0.f,0.f},{0.f,0.f,0.f,0.f}},{{0.f,0.f,0.f,0.f},{0.f,0.f,0.f,0.f}}};
    bf16x8 Bb[4][2], Aa[2][2];
#define C3_LB(slot, it_) { int tap = (it_) >> 2, cc = (it_) & 3; \
    const unsigned short* bp = wB + (size_t)(q0 + r) * 1152 + tap * 128 + cc * 32 + g * 8; \
    Bb[slot][0] = *(const bf16x8*)bp; Bb[slot][1] = *(const bf16x8*)(bp + 16 * 1152); }
#define C3_LA(slot, it_) { int tap = (it_) >> 2, cc = (it_) & 3; \
    int ky = tap / 3, kx = tap - ky * 3; int ch = cc * 4 + g; \
    int px0 = r + kx, px1 = 16 + r + kx; \
    Aa[slot][0] = *(const bf16x8*)&As[(ky * 34 + px0) * 16 + (ch ^ (px0 & 7) ^ (((px0 >> 3) & 1) << 3))]; \
    Aa[slot][1] = *(const bf16x8*)&As[(ky * 34 + px1) * 16 + (ch ^ (px1 & 7) ^ (((px1 >> 3) & 1) << 3))]; }
    C3_LB(0, 0); C3_LB(1, 1); C3_LB(2, 2); C3_LA(0, 0);
    #pragma unroll
    for (int it = 0; it < 36; ++it) {
        if (it + 3 < 36) C3_LB((it + 3) & 3, it + 3);
        if (it + 1 < 36) C3_LA((it + 1) & 1, it + 1);
        int s = it & 3, sa = it & 1;
        acc[0][0] = MFMA16(Aa[sa][0], Bb[s][0], acc[0][0]);
        acc[0][1] = MFMA16(Aa[sa][0], Bb[s][1], acc[0][1]);
        acc[1][0] = MFMA16(Aa[sa][1], Bb[s][0], acc[1][0]);
        acc[1][1] = MFMA16(Aa[sa][1], Bb[s][1], acc[1][1]);
    }
    float bi0 = bias[q0 + r], bi1 = bias[q0 + 16 + r];
    if constexpr (!FQ4) {
        unsigned short* Ob = (unsigned short*)(g_buf + out_off) + (size_t)b * PSTRIDE;
        #pragma unroll
        for (int mt = 0; mt < 2; ++mt)
            #pragma unroll
            for (int reg = 0; reg < 4; ++reg) {
                int j = j0 + mt * 16 + g * 4 + reg;
                size_t base = (size_t)((i + 1) * PADW + j + 1) * H2C;
                Ob[base + q0 + r]      = f2bf(fmaxf(acc[mt][0][reg] + bi0, 0.f));
                Ob[base + q0 + 16 + r] = f2bf(fmaxf(acc[mt][1][reg] + bi1, 0.f));
            }
    } else {
        __shared__ float part[4][2][32];
        float w40a = wq4[q0 + r],       w40b = wq4[q0 + 16 + r];
        float w41a = wq4[128 + q0 + r], w41b = wq4[128 + q0 + 16 + r];
        #pragma unroll
        for (int mt = 0; mt < 2; ++mt)
            #pragma unroll
            for (int reg = 0; reg < 4; ++reg) {
                float x0 = fmaxf(acc[mt][0][reg] + bi0, 0.f);
                float x1 = fmaxf(acc[mt][1][reg] + bi1, 0.f);
                float p0 = x0 * w40a + x1 * w40b;
                float p1 = x0 * w41a + x1 * w41b;
                #pragma unroll
                for (int off = 1; off < 16; off <<= 1) {
                    p0 += __shfl_xor(p0, off);
                    p1 += __shfl_xor(p1, off);
                }
                if (r == 0) {
                    int px = mt * 16 + g * 4 + reg;
                    part[wv][0][px] = p0;
                    part[wv][1][px] = p1;
                }
            }
        __syncthreads();
        if (tid < 64) {
            int px = tid & 31, hd = tid >> 5;
            float s = part[0][hd][px] + part[1][hd][px] + part[2][hd][px] + part[3][hd][px]
                      + bq4[hd];
            out[(size_t)(b * 2 + hd) * IJ + i * 100 + (j0 + px)] = 1.f / (1.f + expf(-s));
        }
    }
}

extern "C" void kernel_launch(void* const* d_in, const int* in_sizes, int n_in,
                              void* d_out, int out_size, void* d_ws, size_t ws_size,
                              hipStream_t stream) {
    const float* x   = (const float*)d_in[0];
    const float* wb1 = (const float*)d_in[1];  const float* bb1 = (const float*)d_in[2];
    const float* wb2 = (const float*)d_in[3];  const float* bb2 = (const float*)d_in[4];
    const float* ws1 = (const float*)d_in[5];  const float* bs1 = (const float*)d_in[6];
    const float* ws2 = (const float*)d_in[7];  const float* bs2 = (const float*)d_in[8];
    const float* we1 = (const float*)d_in[9];  const float* be1 = (const float*)d_in[10];
    const float* we2 = (const float*)d_in[11]; const float* be2 = (const float*)d_in[12];
    const float* wp  = (const float*)d_in[13]; const float* bp  = (const float*)d_in[14];
    const float* w3d = (const float*)d_in[15]; const float* b3d = (const float*)d_in[16];
    const float* wq1 = (const float*)d_in[17]; const float* bq1 = (const float*)d_in[18];
    const float* wq2 = (const float*)d_in[19]; const float* bq2 = (const float*)d_in[20];
    const float* wq3 = (const float*)d_in[21]; const float* bq3 = (const float*)d_in[22];
    const float* wq4 = (const float*)d_in[23]; const float* bq4 = (const float*)d_in[24];
    float* out = (float*)d_out;

    k_prep<<<PREP_IDS / 256, 256, 0, stream>>>(wq1, wq2, wq3, x, b3d, bq1);
    k_w3prep<<<512, 256, 0, stream>>>(w3d);
    k_q1f<<<(BB * IJ * 16 + 255) / 256, 256, 0, stream>>>();
    k_conv_t<100, 64, 400><<<200, 256, 0, stream>>>(OFF_XT, wb1, bb1, OFF_H1);
    k_conv_t<64, 64, 256><<<200, 256, 0, stream>>>(OFF_H1, wb2, bb2, OFF_H2);
    k_conv_se<<<400, 256, 0, stream>>>(ws1, bs1, we1, be1);
    k_heads<<<2, 256, 0, stream>>>(ws2, bs2, we2, be2, out);
    k_conv_pf<<<200, 256, 0, stream>>>(wp, bp);
    k_Am<<<dim3(7, 4, 64), 256, 0, stream>>>();
    k_bm2<<<dim3(10, 64, 2), 256, 0, stream>>>(b3d);
    k_q1m<<<dim3((NVALID + 31) / 32, 2), 256, 0, stream>>>(bq1);
    k_c3m<0><<<dim3(4, 100, 2), 256, 0, stream>>>(OFF_P1, OFF_WQ2B, bq2, OFF_P2,
                                                  nullptr, nullptr, nullptr);
    k_c3m<1><<<dim3(4, 100, 2), 256, 0, stream>>>(OFF_P2, OFF_WQ3B, bq3, 0,
                                                  wq4, bq4, out);
}

// Round 11
// 277.890 us; speedup vs baseline: 1.3104x; 1.0925x over previous
//
#include <hip/hip_runtime.h>
#include <hip/hip_bf16.h>
#include <math.h>

#define TT  100
#define CIN 400
#define H1  256
#define NS  32
#define NP  96
#define H3  512
#define H2C 128
#define BB  2
#define IJ  10000
#define NVALID 5050
#define PADW 102
#define PPIX 10432
#define PSTRIDE (PPIX * H2C)

typedef __attribute__((ext_vector_type(8))) short bf16x8;
typedef __attribute__((ext_vector_type(4))) float f32x4;

// ---- static scratch (float units) ----
#define OFF_XT   0
#define OFF_H1   80000
#define OFF_H2   131200
#define OFF_SB   182400
#define OFF_EB   233600
#define OFF_PF   284800
#define OFF_ATB  336000      // bf16 pairs ATb2[b][64][3200][8][2]
#define OFF_CM2T 3612800     // bf16 [b][ij][512] (valid rows only)
#define OFF_P1   8732800
#define OFF_P2   10068096
#define OFF_CINV 11403392    // uint[64]: c_inv as bf16 pairs
#define OFF_WQ1B 12683392
#define OFF_WQ2B 12716160
#define OFF_WQ3B 12789888
#define OFF_DESC 12863616    // u32 [96][10240]
#define OFF_PFT  13846656    // bf16 [b][112][256]
#define OFF_W3B  13875328    // bf16 [n][o][c]
#define G_TOTAL  15972480

__device__ __align__(16) float g_buf[G_TOTAL];

__device__ inline unsigned short f2bf(float f) {
    __hip_bfloat16 h = __float2bfloat16(f);
    return *(unsigned short*)&h;
}
__device__ inline float bf2f(unsigned short u) {
    union { unsigned int i; float f; } v; v.i = ((unsigned int)u) << 16; return v.f;
}
__device__ inline void dot2(float& acc, unsigned int a, unsigned int w) {
    asm("v_dot2_f32_bf16 %0, %1, %2, %0" : "+v"(acc) : "v"(a), "v"(w));
}
// bank swizzle for bm2 LDS (bijective; SWZ(u)^1 == SWZ(u+1) for even u)
#define SWZ(u) ((u) ^ ((((u) >> 3) ^ ((u) >> 6)) & 7))

// ---------- merged prep: w3prep blocks [0,512) + element-wise prep ----------
#define PREP_IDS (65536 + 147456 + 147456 + 51712 + NP * 10240 + BB * TT * CIN + BB * 12 * 256 + 128)
__global__ __launch_bounds__(256) void k_prepw(
        const float* __restrict__ wq1, const float* __restrict__ wq2,
        const float* __restrict__ wq3, const float* __restrict__ x,
        const float* __restrict__ b3d, const float* __restrict__ bq1,
        const float* __restrict__ w3d) {
    __shared__ float tile[8192];
    int tid = threadIdx.x;
    if (blockIdx.x < 512) {   // w3b[n][o][c] bf16 from w3d[o][c][n]
        int o = blockIdx.x;
        const float* src = w3d + o * 8192;
        for (int idx = tid; idx < 8192; idx += 256) tile[idx] = src[idx];
        __syncthreads();
        int n = tid & 31, ch = tid >> 5;
        unsigned short* w3b = (unsigned short*)(g_buf + OFF_W3B);
        unsigned int w[16];
        #pragma unroll
        for (int c2 = 0; c2 < 16; ++c2) {
            int c = ch * 32 + c2 * 2;
            w[c2] = (unsigned int)f2bf(tile[c * 32 + n]) |
                    ((unsigned int)f2bf(tile[(c + 1) * 32 + n]) << 16);
        }
        uint4* dst = (uint4*)(w3b + ((size_t)n * 512 + o) * 256 + ch * 32);
        dst[0] = make_uint4(w[0], w[1], w[2], w[3]);
        dst[1] = make_uint4(w[4], w[5], w[6], w[7]);
        dst[2] = make_uint4(w[8], w[9], w[10], w[11]);
        dst[3] = make_uint4(w[12], w[13], w[14], w[15]);
        return;
    }
    int id = (blockIdx.x - 512) * 256 + tid;
    if (id < 65536) {
        ((unsigned short*)(g_buf + OFF_WQ1B))[id] = f2bf(wq1[id]);
        return;
    }
    id -= 65536;
    if (id < 147456) {
        int q = id / 1152, k = id % 1152, tap = k >> 7, c = k & 127;
        ((unsigned short*)(g_buf + OFF_WQ2B))[id] = f2bf(wq2[(q * 128 + c) * 9 + tap]);
        return;
    }
    id -= 147456;
    if (id < 147456) {
        int q = id / 1152, k = id % 1152, tap = k >> 7, c = k & 127;
        ((unsigned short*)(g_buf + OFF_WQ3B))[id] = f2bf(wq3[(q * 128 + c) * 9 + tap]);
        return;
    }
    id -= 147456;
    if (id < 51712) {   // halo zero
        int c = id & 31;
        int h = (id >> 5) % 404;
        int bb = ((id >> 5) / 404) & 1;
        int buf = id / 25856;
        int pix;
        if (h < 102) pix = h;
        else if (h < 204) pix = 101 * PADW + (h - 102);
        else { int q = h - 204; pix = (1 + (q >> 1)) * PADW + ((q & 1) ? 101 : 0); }
        unsigned short* P = (unsigned short*)(g_buf + (buf ? OFF_P2 : OFF_P1))
                            + (size_t)bb * PSTRIDE + (size_t)pix * H2C;
        ((uint2*)P)[c] = make_uint2(0u, 0u);
        return;
    }
    id -= 51712;
    if (id < NP * 10240) {   // desc: exact f64 sample math once per (ij,k)
        int k = id / 10240, q = id - k * 10240;
        int i = q / 100, j = q - i * 100;
        unsigned int nb = (unsigned int)((k / 3) * 100);
        unsigned int d;
        if (q >= IJ || i > j) {
            d = nb | (2u << 12);
        } else {
            double len = (double)(j - i + 2);
            double xmn = (double)i - 0.5 * len;
            double xmx = (double)(j + 1) + 0.5 * len;
            double plen = (xmx - xmn) / 95.0;
            double s = __dadd_rn(xmn, __dmul_rn(plen, (double)k));
            double tr = trunc(s);
            double dec = s - tr;
            int dn = (int)tr;
            int up = (int)ceil(s);
            bool okd = (unsigned)dn < (unsigned)TT;
            bool oku = (unsigned)up < (unsigned)TT;
            if (!okd) d = nb | (2u << 12);
            else if (oku && up == dn + 1) {
                unsigned int dfx = (unsigned int)__double2int_rn(dec * 65535.0);
                d = (nb + dn) | (dfx << 16);
            } else if (oku) {
                d = (nb + dn) | (1u << 12);
            } else {
                unsigned int dfx = (unsigned int)__double2int_rn(dec * 65535.0);
                d = (nb + dn) | (1u << 12) | (dfx << 16);
            }
        }
        ((unsigned int*)(g_buf + OFF_DESC))[id] = d;
        return;
    }
    id -= NP * 10240;
    if (id < BB * TT * CIN) {   // x transpose
        int c = id % CIN, t = (id / CIN) % TT, b = id / (CIN * TT);
        g_buf[OFF_XT + (b * CIN + c) * TT + t] = x[id];
        return;
    }
    id -= BB * TT * CIN;
    if (id < BB * 12 * 256) {   // zero pfT pad rows
        int c = id & 255, tp = (id >> 8) % 12, b = id / (12 * 256);
        ((unsigned short*)(g_buf + OFF_PFT))[((size_t)b * 112 + 100 + tp) * 256 + c] = 0;
        return;
    }
    id -= BB * 12 * 256;
    if (id < 128) {   // c_inv[q] = relu(wq1 . relu(b3d) + bq1)
        int q = id;
        float acc = bq1[q];
        const float* wr = wq1 + q * 512;
        #pragma unroll 8
        for (int c = 0; c < 512; ++c) acc = fmaf(wr[c], fmaxf(b3d[c], 0.f), acc);
        acc = fmaxf(acc, 0.f);
        float accO = __shfl_xor(acc, 1);
        if ((id & 1) == 0)
            ((unsigned int*)(g_buf + OFF_CINV))[id >> 1] =
                (unsigned int)f2bf(acc) | ((unsigned int)f2bf(accO) << 16);
    }
}

// ---------- conv1d k=3 pad=1 + relu (128-thread blocks, all CUs busy) ----------
template<int IPG, int OPG, int CINTOT>
__global__ void k_conv_t(int in_off, const float* __restrict__ w,
                         const float* __restrict__ bias, int out_off) {
    int id = blockIdx.x * 128 + threadIdx.x;
    if (id >= BB * H1 * TT) return;
    int t = id % TT, o = (id / TT) % H1, b = id / (TT * H1);
    const float* ip = g_buf + in_off + (b * CINTOT + (o / OPG) * IPG) * TT + t;
    const float* wp = w + o * IPG * 3;
    float a0 = bias[o], a1 = 0.f, a2 = 0.f;
    bool t0 = (t > 0), t1 = (t < TT - 1);
    #pragma unroll 4
    for (int ci = 0; ci < IPG; ++ci) {
        float v0 = t0 ? ip[ci * TT - 1] : 0.f;
        float v1 = ip[ci * TT];
        float v2 = t1 ? ip[ci * TT + 1] : 0.f;
        a0 = fmaf(v0, wp[ci * 3 + 0], a0);
        a1 = fmaf(v1, wp[ci * 3 + 1], a1);
        a2 = fmaf(v2, wp[ci * 3 + 2], a2);
    }
    g_buf[out_off + id] = fmaxf(a0 + a1 + a2, 0.f);
}

// ---------- merged s/e convs + pf conv ----------
__global__ void k_sepf(const float* __restrict__ ws1, const float* __restrict__ bs1,
                       const float* __restrict__ we1, const float* __restrict__ be1,
                       const float* __restrict__ wp, const float* __restrict__ bp) {
    int blk = blockIdx.x;
    if (blk < 400) {   // s (0-199) / e (200-399), grouped 64-ch
        int sec = blk >= 200;
        int id = (blk - sec * 200) * 256 + threadIdx.x;
        if (id >= BB * H1 * TT) return;
        const float* w  = sec ? we1 : ws1;
        const float* bi = sec ? be1 : bs1;
        int out_off = sec ? OFF_EB : OFF_SB;
        int t = id % TT, o = (id / TT) % H1, b = id / (TT * H1);
        const float* ip = g_buf + OFF_H2 + (b * H1 + (o / 64) * 64) * TT + t;
        const float* wpp = w + o * 64 * 3;
        float a0 = bi[o], a1 = 0.f, a2 = 0.f;
        bool tl = (t > 0), th = (t < TT - 1);
        #pragma unroll 4
        for (int ci = 0; ci < 64; ++ci) {
            float v0 = tl ? ip[ci * TT - 1] : 0.f;
            float v1 = ip[ci * TT];
            float v2 = th ? ip[ci * TT + 1] : 0.f;
            a0 = fmaf(v0, wpp[ci * 3 + 0], a0);
            a1 = fmaf(v1, wpp[ci * 3 + 1], a1);
            a2 = fmaf(v2, wpp[ci * 3 + 2], a2);
        }
        g_buf[out_off + id] = fmaxf(a0 + a1 + a2, 0.f);
    } else {           // pf conv (full 256 ch) -> pfT bf16
        int id = (blk - 400) * 256 + threadIdx.x;
        if (id >= BB * H1 * TT) return;
        int t = id % TT, o = (id / TT) % H1, b = id / (TT * H1);
        const float* ip = g_buf + OFF_H2 + (b * H1) * TT + t;
        const float* wpp = wp + o * H1 * 3;
        float a0 = bp[o], a1 = 0.f, a2 = 0.f;
        bool tl = (t > 0), th = (t < TT - 1);
        #pragma unroll 4
        for (int ci = 0; ci < H1; ++ci) {
            float v0 = tl ? ip[ci * TT - 1] : 0.f;
            float v1 = ip[ci * TT];
            float v2 = th ? ip[ci * TT + 1] : 0.f;
            a0 = fmaf(v0, wpp[ci * 3 + 0], a0);
            a1 = fmaf(v1, wpp[ci * 3 + 1], a1);
            a2 = fmaf(v2, wpp[ci * 3 + 2], a2);
        }
        ((unsigned short*)(g_buf + OFF_PFT))[((size_t)b * 112 + t) * 256 + o] =
            f2bf(fmaxf(a0 + a1 + a2, 0.f));
    }
}

// ---------- merged: Am (MFMA A-build) + q1f (P1 invalid fill) + heads ----------
__global__ __launch_bounds__(256) void k_amfh(
        const float* __restrict__ ws2, const float* __restrict__ bs2,
        const float* __restrict__ we2, const float* __restrict__ be2,
        float* __restrict__ out) {
    int blk = blockIdx.x;
    if (blk < 1792) {   // k_Am: ATb2 pairs
        int mt = blk % 7, nt = (blk / 7) % 4, bn = blk / 28;
        int b = bn >> 5, n = bn & 31;
        int wv = threadIdx.x >> 6, lane = threadIdx.x & 63;
        int r = lane & 15, g = lane >> 4;
        const unsigned short* ap = (const unsigned short*)(g_buf + OFF_PFT)
                                   + ((size_t)b * 112 + mt * 16 + r) * 256 + g * 8;
        const unsigned short* bp = (const unsigned short*)(g_buf + OFF_W3B)
                                   + ((size_t)n * 512 + nt * 128 + wv * 32 + r) * 256 + g * 8;
        f32x4 acc0 = {0.f, 0.f, 0.f, 0.f}, acc1 = {0.f, 0.f, 0.f, 0.f};
        #pragma unroll
        for (int ks = 0; ks < 8; ++ks) {
            bf16x8 a  = *(const bf16x8*)(ap + ks * 32);
            bf16x8 b0 = *(const bf16x8*)(bp + ks * 32);
            bf16x8 b1 = *(const bf16x8*)(bp + 16 * 256 + ks * 32);
            acc0 = __builtin_amdgcn_mfma_f32_16x16x32_bf16(a, b0, acc0, 0, 0, 0);
            acc1 = __builtin_amdgcn_mfma_f32_16x16x32_bf16(a, b1, acc1, 0, 0, 0);
        }
        unsigned short* ATb = (unsigned short*)(g_buf + OFF_ATB);
        int o0 = nt * 128 + wv * 32 + r, o1 = o0 + 16;
        #pragma unroll
        for (int reg = 0; reg < 4; ++reg) {
            int t = mt * 16 + g * 4 + reg;
            if (t < TT) {
                size_t m = (size_t)(n * 100 + t);
                unsigned short v0 = f2bf(acc0[reg] * (1.f / 3.f));
                unsigned short v1 = f2bf(acc1[reg] * (1.f / 3.f));
                size_t base0 = ((size_t)(b * 64 + (o0 >> 3)) * 3200 + m) * 16 + (o0 & 7) * 2;
                size_t base1 = ((size_t)(b * 64 + (o1 >> 3)) * 3200 + m) * 16 + (o1 & 7) * 2;
                ATb[base0] = v0;
                ATb[base1] = v1;
                if (t > 0) {
                    ATb[base0 - 16 + 1] = v0;
                    ATb[base1 - 16 + 1] = v1;
                }
                if (t == TT - 1) {
                    ATb[base0 + 1] = 0;
                    ATb[base1 + 1] = 0;
                }
            }
        }
        return;
    }
    if (blk < 1792 + 1250) {   // q1f: P1 invalid-pixel fill with c_inv
        int id = (blk - 1792) * 256 + threadIdx.x;
        if (id >= BB * IJ * 16) return;
        int c = id & 15;
        int q = (id >> 4) % IJ;
        int b = id / (16 * IJ);
        int i = q / 100, j = q - i * 100;
        if (i <= j) return;
        uint4 w = ((const uint4*)(g_buf + OFF_CINV))[c];
        unsigned short* P1 = (unsigned short*)(g_buf + OFF_P1) + (size_t)b * PSTRIDE;
        *(uint4*)(P1 + (size_t)((i + 1) * PADW + j + 1) * H2C + c * 8) = w;
        return;
    }
    {   // heads
        int which = blk - (1792 + 1250);
        const float* w  = which ? we2 : ws2;
        const float* bi = which ? be2 : bs2;
        int in_off = which ? OFF_EB : OFF_SB;
        int id = threadIdx.x;
        if (id >= BB * TT) return;
        int t = id % TT, b = id / TT;
        const float* ip = g_buf + in_off + b * H1 * TT + t;
        float acc = bi[0];
        for (int c = 0; c < H1; ++c) acc = fmaf(ip[c * TT], w[c], acc);
        out[40000 + which * 200 + id] = 1.f / (1.f + expf(-acc));
    }
}

// ---------- BM gather (R8-proven inner loop, deeper bank swizzle) ----------
__global__ __launch_bounds__(256) void k_bm2(const float* __restrict__ b3d) {
    __shared__ uint4 Ash[1600];                 // 25.6 KB; slot = SWZ(u)
    int qt = blockIdx.x, og = blockIdx.y, b = blockIdx.z;
    int tid = threadIdx.x;
    const unsigned int* desc = (const unsigned int*)(g_buf + OFF_DESC);
    const uint4* src = (const uint4*)((const unsigned short*)(g_buf + OFF_ATB)
                                      + (size_t)(b * 64 + og) * 3200 * 16);
    int q[2]; bool val[2];
    #pragma unroll
    for (int u = 0; u < 2; ++u) {
        int v = qt * 512 + u * 256 + tid;
        val[u] = (v < NVALID);
        int vv = val[u] ? v : 0;
        int i = (int)(100.5 - sqrt(10100.25 - 2.0 * (double)vv));
        if (i < 0) i = 0; if (i > 99) i = 99;
        while (100 * (i + 1) - ((i + 1) * i) / 2 <= vv && i < 99) ++i;
        while (100 * i - (i * (i - 1)) / 2 > vv && i > 0) --i;
        int j = i + (vv - (100 * i - (i * (i - 1)) / 2));
        q[u] = i * 100 + j;
    }
    float acc[2][8];
    #pragma unroll
    for (int u = 0; u < 2; ++u)
        #pragma unroll
        for (int c = 0; c < 8; ++c) acc[u][c] = 0.f;

    for (int st = 0; st < 4; ++st) {
        __syncthreads();
        for (int idx = tid; idx < 1600; idx += 256)
            Ash[SWZ(idx)] = src[st * 1600 + idx];
        __syncthreads();
        for (int kk = 0; kk < 24; ++kk) {
            const unsigned int* dk = desc + (size_t)(st * 24 + kk) * 10240;
            #pragma unroll
            for (int u = 0; u < 2; ++u) {
                unsigned int d = dk[q[u]];
                int t = (int)(d & 0xFFFu) - st * 800;
                unsigned int mode = (d >> 12) & 3u;
                float dec = (float)(d >> 16) * (1.f / 65535.f);
                float w0 = (mode == 2u) ? 0.f : 1.f - dec;
                float w1 = (mode == 0u) ? dec : 0.f;
                unsigned int wpair;
                asm("v_cvt_pk_bf16_f32 %0, %1, %2" : "=v"(wpair) : "v"(w0), "v"(w1));
                int u0 = t * 2;
                int s0 = SWZ(u0);
                uint4 A0 = Ash[s0];
                uint4 A1 = Ash[s0 ^ 1];
                dot2(acc[u][0], A0.x, wpair); dot2(acc[u][1], A0.y, wpair);
                dot2(acc[u][2], A0.z, wpair); dot2(acc[u][3], A0.w, wpair);
                dot2(acc[u][4], A1.x, wpair); dot2(acc[u][5], A1.y, wpair);
                dot2(acc[u][6], A1.z, wpair); dot2(acc[u][7], A1.w, wpair);
            }
        }
    }
    unsigned short* cm2T = (unsigned short*)(g_buf + OFF_CM2T);
    #pragma unroll
    for (int u = 0; u < 2; ++u) {
        if (val[u]) {
            unsigned int w[4];
            #pragma unroll
            for (int c2 = 0; c2 < 4; ++c2) {
                float v0 = fmaxf(acc[u][c2 * 2]     + b3d[og * 8 + c2 * 2],     0.f);
                float v1 = fmaxf(acc[u][c2 * 2 + 1] + b3d[og * 8 + c2 * 2 + 1], 0.f);
                w[c2] = (unsigned int)f2bf(v0) | ((unsigned int)f2bf(v1) << 16);
            }
            *(uint4*)(cm2T + ((size_t)b * IJ + q[u]) * 512 + og * 8) =
                make_uint4(w[0], w[1], w[2], w[3]);
        }
    }
}

#define MFMA16(a, b, c) __builtin_amdgcn_mfma_f32_16x16x32_bf16(a, b, c, 0, 0, 0)

// ---------- q1: valid pixels only, pipelined GEMM ----------
__global__ __launch_bounds__(256) void k_q1m(const float* __restrict__ bias) {
    __shared__ uint4 As[2048];
    __shared__ int qmap[32];
    const unsigned short* Acm = (const unsigned short*)(g_buf + OFF_CM2T);
    const unsigned short* Bw  = (const unsigned short*)(g_buf + OFF_WQ1B);
    unsigned short* P1 = (unsigned short*)(g_buf + OFF_P1);
    int m0 = blockIdx.x * 32, b = blockIdx.y;
    int tid = threadIdx.x;
    if (tid < 32) {
        int v = m0 + tid; if (v >= NVALID) v = NVALID - 1;
        int i = (int)(100.5 - sqrt(10100.25 - 2.0 * (double)v));
        if (i < 0) i = 0; if (i > 99) i = 99;
        while (100 * (i + 1) - ((i + 1) * i) / 2 <= v && i < 99) ++i;
        while (100 * i - (i * (i - 1)) / 2 > v && i > 0) --i;
        int j = i + (v - (100 * i - (i * (i - 1)) / 2));
        qmap[tid] = i * 100 + j;
    }
    __syncthreads();
    for (int idx = tid; idx < 2048; idx += 256) {
        int px = idx >> 6, ch = idx & 63;
        int ch2 = ch ^ (px & 7) ^ (((px >> 3) & 1) << 3);
        As[px * 64 + ch2] = *(const uint4*)(Acm + ((size_t)b * IJ + qmap[px]) * 512 + ch * 8);
    }
    __syncthreads();
    int wv = tid >> 6, lane = tid & 63, r = lane & 15, g = lane >> 4;
    int q0 = wv * 32;
    f32x4 acc[2][2] = {{{0.f,0.f,0.f,0.f},{0.f,0.f,0.f,0.f}},{{0.f,0.f,0.f,0.f},{0.f,0.f,0.f,0.f}}};
    bf16x8 Bb[4][2], Aa[2][2];
#define Q1_LB(slot, it_) { const unsigned short* bp = Bw + (size_t)(q0 + r) * 512 + (it_) * 32 + g * 8; \
    Bb[slot][0] = *(const bf16x8*)bp; Bb[slot][1] = *(const bf16x8*)(bp + 16 * 512); }
#define Q1_LA(slot, it_) { int ch = (it_) * 4 + g; \
    int px0 = r, px1 = 16 + r; \
    Aa[slot][0] = *(const bf16x8*)&As[px0 * 64 + (ch ^ (px0 & 7) ^ (((px0 >> 3) & 1) << 3))]; \
    Aa[slot][1] = *(const bf16x8*)&As[px1 * 64 + (ch ^ (px1 & 7) ^ (((px1 >> 3) & 1) << 3))]; }
    Q1_LB(0, 0); Q1_LB(1, 1); Q1_LB(2, 2); Q1_LA(0, 0);
    #pragma unroll
    for (int it = 0; it < 16; ++it) {
        if (it + 3 < 16) Q1_LB((it + 3) & 3, it + 3);
        if (it + 1 < 16) Q1_LA((it + 1) & 1, it + 1);
        int s = it & 3, sa = it & 1;
        acc[0][0] = MFMA16(Aa[sa][0], Bb[s][0], acc[0][0]);
        acc[0][1] = MFMA16(Aa[sa][0], Bb[s][1], acc[0][1]);
        acc[1][0] = MFMA16(Aa[sa][1], Bb[s][0], acc[1][0]);
        acc[1][1] = MFMA16(Aa[sa][1], Bb[s][1], acc[1][1]);
    }
    float bi0 = bias[q0 + r], bi1 = bias[q0 + 16 + r];
    unsigned short* Pout = P1 + (size_t)b * PSTRIDE;
    #pragma unroll
    for (int mt = 0; mt < 2; ++mt)
        #pragma unroll
        for (int reg = 0; reg < 4; ++reg) {
            int px = mt * 16 + g * 4 + reg;
            if (m0 + px < NVALID) {
                int q = qmap[px];
                int i = q / 100, j = q - i * 100;
                size_t base = (size_t)((i + 1) * PADW + j + 1) * H2C;
                Pout[base + q0 + r]      = f2bf(fmaxf(acc[mt][0][reg] + bi0, 0.f));
                Pout[base + q0 + 16 + r] = f2bf(fmaxf(acc[mt][1][reg] + bi1, 0.f));
            }
        }
}

// ---------- 3x3 conv 128->128, pipelined; FQ4: fuse 1x1->2 + sigmoid ----------
template<int FQ4>
__global__ __launch_bounds__(256) void k_c3m(int in_off, int w_off,
                                             const float* __restrict__ bias,
                                             int out_off,
                                             const float* __restrict__ wq4,
                                             const float* __restrict__ bq4,
                                             float* __restrict__ out) {
    __shared__ uint4 As[1632];
    const unsigned short* Pin = (const unsigned short*)(g_buf + in_off);
    const unsigned short* wB  = (const unsigned short*)(g_buf + w_off);
    int jt = blockIdx.x, i = blockIdx.y, b = blockIdx.z;
    int j0 = (jt == 3) ? 68 : jt * 32;
    int tid = threadIdx.x;
    const unsigned short* Ab = Pin + (size_t)b * PSTRIDE;
    for (int idx = tid; idx < 1632; idx += 256) {
        int ky = idx / 544, rem = idx - ky * 544;
        int px = rem >> 4, ch = rem & 15;
        int ch2 = ch ^ (px & 7) ^ (((px >> 3) & 1) << 3);
        As[(ky * 34 + px) * 16 + ch2] =
            *(const uint4*)(Ab + (size_t)((i + ky) * PADW + j0 + px) * H2C + ch * 8);
    }
    __syncthreads();
    int wv = tid >> 6, lane = tid & 63, r = lane & 15, g = lane >> 4;
    int q0 = wv * 32;
    f32x4 acc[2][2] = {{{0.f,0.f,0.f,0.f},{0.f,0.f,0.f,0.f}},{{0.f,0.f,0.f,0.f},{0.f,0.f,0.f,0.f}}};
    bf16x8 Bb[4][2], Aa[2][2];
#define C3_LB(slot, it_) { int tap = (it_) >> 2, cc = (it_) & 3; \
    const unsigned short* bp = wB + (size_t)(q0 + r) * 1152 + tap * 128 + cc * 32 + g * 8; \
    Bb[slot][0] = *(const bf16x8*)bp; Bb[slot][1] = *(const bf16x8*)(bp + 16 * 1152); }
#define C3_LA(slot, it_) { int tap = (it_) >> 2, cc = (it_) & 3; \
    int ky = tap / 3, kx = tap - ky * 3; int ch = cc * 4 + g; \
    int px0 = r + kx, px1 = 16 + r + kx; \
    Aa[slot][0] = *(const bf16x8*)&As[(ky * 34 + px0) * 16 + (ch ^ (px0 & 7) ^ (((px0 >> 3) & 1) << 3))]; \
    Aa[slot][1] = *(const bf16x8*)&As[(ky * 34 + px1) * 16 + (ch ^ (px1 & 7) ^ (((px1 >> 3) & 1) << 3))]; }
    C3_LB(0, 0); C3_LB(1, 1); C3_LB(2, 2); C3_LA(0, 0);
    #pragma unroll
    for (int it = 0; it < 36; ++it) {
        if (it + 3 < 36) C3_LB((it + 3) & 3, it + 3);
        if (it + 1 < 36) C3_LA((it + 1) & 1, it + 1);
        int s = it & 3, sa = it & 1;
        acc[0][0] = MFMA16(Aa[sa][0], Bb[s][0], acc[0][0]);
        acc[0][1] = MFMA16(Aa[sa][0], Bb[s][1], acc[0][1]);
        acc[1][0] = MFMA16(Aa[sa][1], Bb[s][0], acc[1][0]);
        acc[1][1] = MFMA16(Aa[sa][1], Bb[s][1], acc[1][1]);
    }
    float bi0 = bias[q0 + r], bi1 = bias[q0 + 16 + r];
    if constexpr (!FQ4) {
        unsigned short* Ob = (unsigned short*)(g_buf + out_off) + (size_t)b * PSTRIDE;
        #pragma unroll
        for (int mt = 0; mt < 2; ++mt)
            #pragma unroll
            for (int reg = 0; reg < 4; ++reg) {
                int j = j0 + mt * 16 + g * 4 + reg;
                size_t base = (size_t)((i + 1) * PADW + j + 1) * H2C;
                Ob[base + q0 + r]      = f2bf(fmaxf(acc[mt][0][reg] + bi0, 0.f));
                Ob[base + q0 + 16 + r] = f2bf(fmaxf(acc[mt][1][reg] + bi1, 0.f));
            }
    } else {
        __shared__ float part[4][2][32];
        float w40a = wq4[q0 + r],       w40b = wq4[q0 + 16 + r];
        float w41a = wq4[128 + q0 + r], w41b = wq4[128 + q0 + 16 + r];
        #pragma unroll
        for (int mt = 0; mt < 2; ++mt)
            #pragma unroll
            for (int reg = 0; reg < 4; ++reg) {
                float x0 = fmaxf(acc[mt][0][reg] + bi0, 0.f);
                float x1 = fmaxf(acc[mt][1][reg] + bi1, 0.f);
                float p0 = x0 * w40a + x1 * w40b;
                float p1 = x0 * w41a + x1 * w41b;
                #pragma unroll
                for (int off = 1; off < 16; off <<= 1) {
                    p0 += __shfl_xor(p0, off);
                    p1 += __shfl_xor(p1, off);
                }
                if (r == 0) {
                    int px = mt * 16 + g * 4 + reg;
                    part[wv][0][px] = p0;
                    part[wv][1][px] = p1;
                }
            }
        __syncthreads();
        if (tid < 64) {
            int px = tid & 31, hd = tid >> 5;
            float s = part[0][hd][px] + part[1][hd][px] + part[2][hd][px] + part[3][hd][px]
                      + bq4[hd];
            out[(size_t)(b * 2 + hd) * IJ + i * 100 + (j0 + px)] = 1.f / (1.f + expf(-s));
        }
    }
}

extern "C" void kernel_launch(void* const* d_in, const int* in_sizes, int n_in,
                              void* d_out, int out_size, void* d_ws, size_t ws_size,
                              hipStream_t stream) {
    const float* x   = (const float*)d_in[0];
    const float* wb1 = (const float*)d_in[1];  const float* bb1 = (const float*)d_in[2];
    const float* wb2 = (const float*)d_in[3];  const float* bb2 = (const float*)d_in[4];
    const float* ws1 = (const float*)d_in[5];  const float* bs1 = (const float*)d_in[6];
    const float* ws2 = (const float*)d_in[7];  const float* bs2 = (const float*)d_in[8];
    const float* we1 = (const float*)d_in[9];  const float* be1 = (const float*)d_in[10];
    const float* we2 = (const float*)d_in[11]; const float* be2 = (const float*)d_in[12];
    const float* wp  = (const float*)d_in[13]; const float* bp  = (const float*)d_in[14];
    const float* w3d = (const float*)d_in[15]; const float* b3d = (const float*)d_in[16];
    const float* wq1 = (const float*)d_in[17]; const float* bq1 = (const float*)d_in[18];
    const float* wq2 = (const float*)d_in[19]; const float* bq2 = (const float*)d_in[20];
    const float* wq3 = (const float*)d_in[21]; const float* bq3 = (const float*)d_in[22];
    const float* wq4 = (const float*)d_in[23]; const float* bq4 = (const float*)d_in[24];
    float* out = (float*)d_out;

    k_prepw<<<512 + PREP_IDS / 256, 256, 0, stream>>>(wq1, wq2, wq3, x, b3d, bq1, w3d);
    k_conv_t<100, 64, 400><<<400, 128, 0, stream>>>(OFF_XT, wb1, bb1, OFF_H1);
    k_conv_t<64, 64, 256><<<400, 128, 0, stream>>>(OFF_H1, wb2, bb2, OFF_H2);
    k_sepf<<<600, 256, 0, stream>>>(ws1, bs1, we1, be1, wp, bp);
    k_amfh<<<1792 + 1250 + 2, 256, 0, stream>>>(ws2, bs2, we2, be2, out);
    k_bm2<<<dim3(10, 64, 2), 256, 0, stream>>>(b3d);
    k_q1m<<<dim3((NVALID + 31) / 32, 2), 256, 0, stream>>>(bq1);
    k_c3m<0><<<dim3(4, 100, 2), 256, 0, stream>>>(OFF_P1, OFF_WQ2B, bq2, OFF_P2,
                                                  nullptr, nullptr, nullptr);
    k_c3m<1><<<dim3(4, 100, 2), 256, 0, stream>>>(OFF_P2, OFF_WQ3B, bq3, 0,
                                                  wq4, bq4, out);
}

// Round 12
// 273.670 us; speedup vs baseline: 1.3306x; 1.0154x over previous
//
#include <hip/hip_runtime.h>
#include <hip/hip_bf16.h>
#include <math.h>

#define TT  100
#define CIN 400
#define H1  256
#define NS  32
#define NP  96
#define H3  512
#define H2C 128
#define BB  2
#define IJ  10000
#define NVALID 5050
#define PADW 102
#define PPIX 10432
#define PSTRIDE (PPIX * H2C)

typedef __attribute__((ext_vector_type(8))) short bf16x8;
typedef __attribute__((ext_vector_type(4))) float f32x4;

// ---- static scratch (float units) ----
#define OFF_XT   0
#define OFF_H1   80000
#define OFF_H2   131200
#define OFF_SB   182400
#define OFF_EB   233600
#define OFF_PF   284800
#define OFF_ATB  336000      // bf16 pairs ATb[b][16 og32][3200 m][32ch][2]
#define OFF_CM2T 3612800     // bf16 [b][ij][512] (valid rows only)
#define OFF_P1   8732800
#define OFF_P2   10068096
#define OFF_CINV 11403392    // uint[64]: c_inv as bf16 pairs
#define OFF_WQ1B 12683392
#define OFF_WQ2B 12716160
#define OFF_WQ3B 12789888
#define OFF_DESC 12863616    // u32 [96][10240]
#define OFF_PFT  13846656    // bf16 [b][112][256]
#define OFF_W3B  13875328    // bf16 [n][o][c]
#define G_TOTAL  15972480

__device__ __align__(16) float g_buf[G_TOTAL];

__device__ inline unsigned short f2bf(float f) {
    __hip_bfloat16 h = __float2bfloat16(f);
    return *(unsigned short*)&h;
}
__device__ inline float bf2f(unsigned short u) {
    union { unsigned int i; float f; } v; v.i = ((unsigned int)u) << 16; return v.f;
}
__device__ inline void dot2(float& acc, unsigned int a, unsigned int w) {
    asm("v_dot2_f32_bf16 %0, %1, %2, %0" : "+v"(acc) : "v"(a), "v"(w));
}

// ---------- merged prep: w3prep blocks [0,512) + element-wise prep ----------
#define PREP_IDS (65536 + 147456 + 147456 + 51712 + NP * 10240 + BB * TT * CIN + BB * 12 * 256 + 128)
__global__ __launch_bounds__(256) void k_prepw(
        const float* __restrict__ wq1, const float* __restrict__ wq2,
        const float* __restrict__ wq3, const float* __restrict__ x,
        const float* __restrict__ b3d, const float* __restrict__ bq1,
        const float* __restrict__ w3d) {
    __shared__ float tile[8192];
    int tid = threadIdx.x;
    if (blockIdx.x < 512) {   // w3b[n][o][c] bf16 from w3d[o][c][n]
        int o = blockIdx.x;
        const float* src = w3d + o * 8192;
        for (int idx = tid; idx < 8192; idx += 256) tile[idx] = src[idx];
        __syncthreads();
        int n = tid & 31, ch = tid >> 5;
        unsigned short* w3b = (unsigned short*)(g_buf + OFF_W3B);
        unsigned int w[16];
        #pragma unroll
        for (int c2 = 0; c2 < 16; ++c2) {
            int c = ch * 32 + c2 * 2;
            w[c2] = (unsigned int)f2bf(tile[c * 32 + n]) |
                    ((unsigned int)f2bf(tile[(c + 1) * 32 + n]) << 16);
        }
        uint4* dst = (uint4*)(w3b + ((size_t)n * 512 + o) * 256 + ch * 32);
        dst[0] = make_uint4(w[0], w[1], w[2], w[3]);
        dst[1] = make_uint4(w[4], w[5], w[6], w[7]);
        dst[2] = make_uint4(w[8], w[9], w[10], w[11]);
        dst[3] = make_uint4(w[12], w[13], w[14], w[15]);
        return;
    }
    int id = (blockIdx.x - 512) * 256 + tid;
    if (id < 65536) {
        ((unsigned short*)(g_buf + OFF_WQ1B))[id] = f2bf(wq1[id]);
        return;
    }
    id -= 65536;
    if (id < 147456) {
        int q = id / 1152, k = id % 1152, tap = k >> 7, c = k & 127;
        ((unsigned short*)(g_buf + OFF_WQ2B))[id] = f2bf(wq2[(q * 128 + c) * 9 + tap]);
        return;
    }
    id -= 147456;
    if (id < 147456) {
        int q = id / 1152, k = id % 1152, tap = k >> 7, c = k & 127;
        ((unsigned short*)(g_buf + OFF_WQ3B))[id] = f2bf(wq3[(q * 128 + c) * 9 + tap]);
        return;
    }
    id -= 147456;
    if (id < 51712) {   // halo zero
        int c = id & 31;
        int h = (id >> 5) % 404;
        int bb = ((id >> 5) / 404) & 1;
        int buf = id / 25856;
        int pix;
        if (h < 102) pix = h;
        else if (h < 204) pix = 101 * PADW + (h - 102);
        else { int q = h - 204; pix = (1 + (q >> 1)) * PADW + ((q & 1) ? 101 : 0); }
        unsigned short* P = (unsigned short*)(g_buf + (buf ? OFF_P2 : OFF_P1))
                            + (size_t)bb * PSTRIDE + (size_t)pix * H2C;
        ((uint2*)P)[c] = make_uint2(0u, 0u);
        return;
    }
    id -= 51712;
    if (id < NP * 10240) {   // desc: exact f64 sample math once per (ij,k)
        int k = id / 10240, q = id - k * 10240;
        int i = q / 100, j = q - i * 100;
        unsigned int nb = (unsigned int)((k / 3) * 100);
        unsigned int d;
        if (q >= IJ || i > j) {
            d = nb | (2u << 12);
        } else {
            double len = (double)(j - i + 2);
            double xmn = (double)i - 0.5 * len;
            double xmx = (double)(j + 1) + 0.5 * len;
            double plen = (xmx - xmn) / 95.0;
            double s = __dadd_rn(xmn, __dmul_rn(plen, (double)k));
            double tr = trunc(s);
            double dec = s - tr;
            int dn = (int)tr;
            int up = (int)ceil(s);
            bool okd = (unsigned)dn < (unsigned)TT;
            bool oku = (unsigned)up < (unsigned)TT;
            if (!okd) d = nb | (2u << 12);
            else if (oku && up == dn + 1) {
                unsigned int dfx = (unsigned int)__double2int_rn(dec * 65535.0);
                d = (nb + dn) | (dfx << 16);
            } else if (oku) {
                d = (nb + dn) | (1u << 12);
            } else {
                unsigned int dfx = (unsigned int)__double2int_rn(dec * 65535.0);
                d = (nb + dn) | (1u << 12) | (dfx << 16);
            }
        }
        ((unsigned int*)(g_buf + OFF_DESC))[id] = d;
        return;
    }
    id -= NP * 10240;
    if (id < BB * TT * CIN) {   // x transpose
        int c = id % CIN, t = (id / CIN) % TT, b = id / (CIN * TT);
        g_buf[OFF_XT + (b * CIN + c) * TT + t] = x[id];
        return;
    }
    id -= BB * TT * CIN;
    if (id < BB * 12 * 256) {   // zero pfT pad rows
        int c = id & 255, tp = (id >> 8) % 12, b = id / (12 * 256);
        ((unsigned short*)(g_buf + OFF_PFT))[((size_t)b * 112 + 100 + tp) * 256 + c] = 0;
        return;
    }
    id -= BB * 12 * 256;
    if (id < 128) {   // c_inv[q] = relu(wq1 . relu(b3d) + bq1)
        int q = id;
        float acc = bq1[q];
        const float* wr = wq1 + q * 512;
        #pragma unroll 8
        for (int c = 0; c < 512; ++c) acc = fmaf(wr[c], fmaxf(b3d[c], 0.f), acc);
        acc = fmaxf(acc, 0.f);
        float accO = __shfl_xor(acc, 1);
        if ((id & 1) == 0)
            ((unsigned int*)(g_buf + OFF_CINV))[id >> 1] =
                (unsigned int)f2bf(acc) | ((unsigned int)f2bf(accO) << 16);
    }
}

// ---------- conv1d k=3 pad=1 + relu (128-thread blocks) ----------
template<int IPG, int OPG, int CINTOT>
__global__ void k_conv_t(int in_off, const float* __restrict__ w,
                         const float* __restrict__ bias, int out_off) {
    int id = blockIdx.x * 128 + threadIdx.x;
    if (id >= BB * H1 * TT) return;
    int t = id % TT, o = (id / TT) % H1, b = id / (TT * H1);
    const float* ip = g_buf + in_off + (b * CINTOT + (o / OPG) * IPG) * TT + t;
    const float* wp = w + o * IPG * 3;
    float a0 = bias[o], a1 = 0.f, a2 = 0.f;
    bool t0 = (t > 0), t1 = (t < TT - 1);
    #pragma unroll 4
    for (int ci = 0; ci < IPG; ++ci) {
        float v0 = t0 ? ip[ci * TT - 1] : 0.f;
        float v1 = ip[ci * TT];
        float v2 = t1 ? ip[ci * TT + 1] : 0.f;
        a0 = fmaf(v0, wp[ci * 3 + 0], a0);
        a1 = fmaf(v1, wp[ci * 3 + 1], a1);
        a2 = fmaf(v2, wp[ci * 3 + 2], a2);
    }
    g_buf[out_off + id] = fmaxf(a0 + a1 + a2, 0.f);
}

// ---------- merged s/e convs + pf conv ----------
__global__ void k_sepf(const float* __restrict__ ws1, const float* __restrict__ bs1,
                       const float* __restrict__ we1, const float* __restrict__ be1,
                       const float* __restrict__ wp, const float* __restrict__ bp) {
    int blk = blockIdx.x;
    if (blk < 400) {
        int sec = blk >= 200;
        int id = (blk - sec * 200) * 256 + threadIdx.x;
        if (id >= BB * H1 * TT) return;
        const float* w  = sec ? we1 : ws1;
        const float* bi = sec ? be1 : bs1;
        int out_off = sec ? OFF_EB : OFF_SB;
        int t = id % TT, o = (id / TT) % H1, b = id / (TT * H1);
        const float* ip = g_buf + OFF_H2 + (b * H1 + (o / 64) * 64) * TT + t;
        const float* wpp = w + o * 64 * 3;
        float a0 = bi[o], a1 = 0.f, a2 = 0.f;
        bool tl = (t > 0), th = (t < TT - 1);
        #pragma unroll 4
        for (int ci = 0; ci < 64; ++ci) {
            float v0 = tl ? ip[ci * TT - 1] : 0.f;
            float v1 = ip[ci * TT];
            float v2 = th ? ip[ci * TT + 1] : 0.f;
            a0 = fmaf(v0, wpp[ci * 3 + 0], a0);
            a1 = fmaf(v1, wpp[ci * 3 + 1], a1);
            a2 = fmaf(v2, wpp[ci * 3 + 2], a2);
        }
        g_buf[out_off + id] = fmaxf(a0 + a1 + a2, 0.f);
    } else {
        int id = (blk - 400) * 256 + threadIdx.x;
        if (id >= BB * H1 * TT) return;
        int t = id % TT, o = (id / TT) % H1, b = id / (TT * H1);
        const float* ip = g_buf + OFF_H2 + (b * H1) * TT + t;
        const float* wpp = wp + o * H1 * 3;
        float a0 = bp[o], a1 = 0.f, a2 = 0.f;
        bool tl = (t > 0), th = (t < TT - 1);
        #pragma unroll 4
        for (int ci = 0; ci < H1; ++ci) {
            float v0 = tl ? ip[ci * TT - 1] : 0.f;
            float v1 = ip[ci * TT];
            float v2 = th ? ip[ci * TT + 1] : 0.f;
            a0 = fmaf(v0, wpp[ci * 3 + 0], a0);
            a1 = fmaf(v1, wpp[ci * 3 + 1], a1);
            a2 = fmaf(v2, wpp[ci * 3 + 2], a2);
        }
        ((unsigned short*)(g_buf + OFF_PFT))[((size_t)b * 112 + t) * 256 + o] =
            f2bf(fmaxf(a0 + a1 + a2, 0.f));
    }
}

// ---------- merged: Am (MFMA A-build, og32 layout) + q1f + heads ----------
__global__ __launch_bounds__(256) void k_amfh(
        const float* __restrict__ ws2, const float* __restrict__ bs2,
        const float* __restrict__ we2, const float* __restrict__ be2,
        float* __restrict__ out) {
    int blk = blockIdx.x;
    if (blk < 1792) {   // k_Am: ATb pairs, rows of 32 ch (64B)
        int mt = blk % 7, nt = (blk / 7) % 4, bn = blk / 28;
        int b = bn >> 5, n = bn & 31;
        int wv = threadIdx.x >> 6, lane = threadIdx.x & 63;
        int r = lane & 15, g = lane >> 4;
        const unsigned short* ap = (const unsigned short*)(g_buf + OFF_PFT)
                                   + ((size_t)b * 112 + mt * 16 + r) * 256 + g * 8;
        const unsigned short* bp = (const unsigned short*)(g_buf + OFF_W3B)
                                   + ((size_t)n * 512 + nt * 128 + wv * 32 + r) * 256 + g * 8;
        f32x4 acc0 = {0.f, 0.f, 0.f, 0.f}, acc1 = {0.f, 0.f, 0.f, 0.f};
        #pragma unroll
        for (int ks = 0; ks < 8; ++ks) {
            bf16x8 a  = *(const bf16x8*)(ap + ks * 32);
            bf16x8 b0 = *(const bf16x8*)(bp + ks * 32);
            bf16x8 b1 = *(const bf16x8*)(bp + 16 * 256 + ks * 32);
            acc0 = __builtin_amdgcn_mfma_f32_16x16x32_bf16(a, b0, acc0, 0, 0, 0);
            acc1 = __builtin_amdgcn_mfma_f32_16x16x32_bf16(a, b1, acc1, 0, 0, 0);
        }
        unsigned short* ATb = (unsigned short*)(g_buf + OFF_ATB);
        int og = nt * 4 + wv;                    // o0=nt*128+wv*32+r -> og=o>>5 (r<16)
        size_t gb = (size_t)(b * 16 + og) * 3200;
        #pragma unroll
        for (int reg = 0; reg < 4; ++reg) {
            int t = mt * 16 + g * 4 + reg;
            if (t < TT) {
                size_t m = (size_t)(n * 100 + t);
                unsigned short v0 = f2bf(acc0[reg] * (1.f / 3.f));
                unsigned short v1 = f2bf(acc1[reg] * (1.f / 3.f));
                size_t base0 = (gb + m) * 64 + (size_t)r * 2;          // c32 = r
                size_t base1 = (gb + m) * 64 + (size_t)(16 + r) * 2;   // c32 = 16+r
                ATb[base0] = v0;
                ATb[base1] = v1;
                if (t > 0) {
                    ATb[base0 - 64 + 1] = v0;
                    ATb[base1 - 64 + 1] = v1;
                }
                if (t == TT - 1) {
                    ATb[base0 + 1] = 0;
                    ATb[base1 + 1] = 0;
                }
            }
        }
        return;
    }
    if (blk < 1792 + 1250) {   // q1f: P1 invalid-pixel fill with c_inv
        int id = (blk - 1792) * 256 + threadIdx.x;
        if (id >= BB * IJ * 16) return;
        int c = id & 15;
        int q = (id >> 4) % IJ;
        int b = id / (16 * IJ);
        int i = q / 100, j = q - i * 100;
        if (i <= j) return;
        uint4 w = ((const uint4*)(g_buf + OFF_CINV))[c];
        unsigned short* P1 = (unsigned short*)(g_buf + OFF_P1) + (size_t)b * PSTRIDE;
        *(uint4*)(P1 + (size_t)((i + 1) * PADW + j + 1) * H2C + c * 8) = w;
        return;
    }
    {   // heads
        int which = blk - (1792 + 1250);
        const float* w  = which ? we2 : ws2;
        const float* bi = which ? be2 : bs2;
        int in_off = which ? OFF_EB : OFF_SB;
        int id = threadIdx.x;
        if (id >= BB * TT) return;
        int t = id % TT, b = id / TT;
        const float* ip = g_buf + in_off + b * H1 * TT + t;
        float acc = bi[0];
        for (int c = 0; c < H1; ++c) acc = fmaf(ip[c * TT], w[c], acc);
        out[40000 + which * 200 + id] = 1.f / (1.f + expf(-acc));
    }
}

// ---------- BM gather: 32 ch/block (decode amortized 4x), 200-row windows ----------
__global__ __launch_bounds__(256) void k_bm2(const float* __restrict__ b3d) {
    __shared__ uint4 Ash[1600];                 // 200 rows x 8 quads; slot=(qd+t)&7
    int qt = blockIdx.x, og = blockIdx.y, b = blockIdx.z;
    int tid = threadIdx.x;
    int v = qt * 256 + tid;
    bool val = (v < NVALID);
    int vv = val ? v : 0;
    int i = (int)(100.5 - sqrt(10100.25 - 2.0 * (double)vv));
    if (i < 0) i = 0; if (i > 99) i = 99;
    while (100 * (i + 1) - ((i + 1) * i) / 2 <= vv && i < 99) ++i;
    while (100 * i - (i * (i - 1)) / 2 > vv && i > 0) --i;
    int j = i + (vv - (100 * i - (i * (i - 1)) / 2));
    int qv = i * 100 + j;
    const unsigned int* desc = (const unsigned int*)(g_buf + OFF_DESC);
    const uint4* src = (const uint4*)((const unsigned short*)(g_buf + OFF_ATB)
                                      + (size_t)(b * 16 + og) * 3200 * 64);
    float acc[32];
    #pragma unroll
    for (int c = 0; c < 32; ++c) acc[c] = 0.f;

    for (int st = 0; st < 16; ++st) {
        __syncthreads();
        for (int idx = tid; idx < 1600; idx += 256) {
            int t = idx >> 3, qd = idx & 7;
            Ash[(t << 3) | ((qd + t) & 7)] = src[st * 1600 + idx];
        }
        __syncthreads();
        #pragma unroll
        for (int kk = 0; kk < 6; ++kk) {
            unsigned int d = desc[(size_t)(st * 6 + kk) * 10240 + qv];
            int t2 = (int)(d & 0xFFFu) - st * 200;
            unsigned int mode = (d >> 12) & 3u;
            float dec = (float)(d >> 16) * (1.f / 65535.f);
            float w0 = (mode == 2u) ? 0.f : 1.f - dec;
            float w1 = (mode == 0u) ? dec : 0.f;
            unsigned int wpair;
            asm("v_cvt_pk_bf16_f32 %0, %1, %2" : "=v"(wpair) : "v"(w0), "v"(w1));
            int base = t2 << 3;
            uint4 A0 = Ash[base | ((0 + t2) & 7)];
            uint4 A1 = Ash[base | ((1 + t2) & 7)];
            uint4 A2 = Ash[base | ((2 + t2) & 7)];
            uint4 A3 = Ash[base | ((3 + t2) & 7)];
            uint4 A4 = Ash[base | ((4 + t2) & 7)];
            uint4 A5 = Ash[base | ((5 + t2) & 7)];
            uint4 A6 = Ash[base | ((6 + t2) & 7)];
            uint4 A7 = Ash[base | ((7 + t2) & 7)];
            dot2(acc[0],  A0.x, wpair); dot2(acc[1],  A0.y, wpair);
            dot2(acc[2],  A0.z, wpair); dot2(acc[3],  A0.w, wpair);
            dot2(acc[4],  A1.x, wpair); dot2(acc[5],  A1.y, wpair);
            dot2(acc[6],  A1.z, wpair); dot2(acc[7],  A1.w, wpair);
            dot2(acc[8],  A2.x, wpair); dot2(acc[9],  A2.y, wpair);
            dot2(acc[10], A2.z, wpair); dot2(acc[11], A2.w, wpair);
            dot2(acc[12], A3.x, wpair); dot2(acc[13], A3.y, wpair);
            dot2(acc[14], A3.z, wpair); dot2(acc[15], A3.w, wpair);
            dot2(acc[16], A4.x, wpair); dot2(acc[17], A4.y, wpair);
            dot2(acc[18], A4.z, wpair); dot2(acc[19], A4.w, wpair);
            dot2(acc[20], A5.x, wpair); dot2(acc[21], A5.y, wpair);
            dot2(acc[22], A5.z, wpair); dot2(acc[23], A5.w, wpair);
            dot2(acc[24], A6.x, wpair); dot2(acc[25], A6.y, wpair);
            dot2(acc[26], A6.z, wpair); dot2(acc[27], A6.w, wpair);
            dot2(acc[28], A7.x, wpair); dot2(acc[29], A7.y, wpair);
            dot2(acc[30], A7.z, wpair); dot2(acc[31], A7.w, wpair);
        }
    }
    if (val) {
        unsigned short* cm2T = (unsigned short*)(g_buf + OFF_CM2T);
        unsigned int w[16];
        #pragma unroll
        for (int c2 = 0; c2 < 16; ++c2) {
            float x0 = fmaxf(acc[c2 * 2]     + b3d[og * 32 + c2 * 2],     0.f);
            float x1 = fmaxf(acc[c2 * 2 + 1] + b3d[og * 32 + c2 * 2 + 1], 0.f);
            w[c2] = (unsigned int)f2bf(x0) | ((unsigned int)f2bf(x1) << 16);
        }
        uint4* dst = (uint4*)(cm2T + ((size_t)b * IJ + qv) * 512 + og * 32);
        dst[0] = make_uint4(w[0],  w[1],  w[2],  w[3]);
        dst[1] = make_uint4(w[4],  w[5],  w[6],  w[7]);
        dst[2] = make_uint4(w[8],  w[9],  w[10], w[11]);
        dst[3] = make_uint4(w[12], w[13], w[14], w[15]);
    }
}

#define MFMA16(a, b, c) __builtin_amdgcn_mfma_f32_16x16x32_bf16(a, b, c, 0, 0, 0)

// ---------- q1: valid pixels only, pipelined GEMM ----------
__global__ __launch_bounds__(256) void k_q1m(const float* __restrict__ bias) {
    __shared__ uint4 As[2048];
    __shared__ int qmap[32];
    const unsigned short* Acm = (const unsigned short*)(g_buf + OFF_CM2T);
    const unsigned short* Bw  = (const unsigned short*)(g_buf + OFF_WQ1B);
    unsigned short* P1 = (unsigned short*)(g_buf + OFF_P1);
    int m0 = blockIdx.x * 32, b = blockIdx.y;
    int tid = threadIdx.x;
    if (tid < 32) {
        int v = m0 + tid; if (v >= NVALID) v = NVALID - 1;
        int i = (int)(100.5 - sqrt(10100.25 - 2.0 * (double)v));
        if (i < 0) i = 0; if (i > 99) i = 99;
        while (100 * (i + 1) - ((i + 1) * i) / 2 <= v && i < 99) ++i;
        while (100 * i - (i * (i - 1)) / 2 > v && i > 0) --i;
        int j = i + (v - (100 * i - (i * (i - 1)) / 2));
        qmap[tid] = i * 100 + j;
    }
    __syncthreads();
    for (int idx = tid; idx < 2048; idx += 256) {
        int px = idx >> 6, ch = idx & 63;
        int ch2 = ch ^ (px & 7) ^ (((px >> 3) & 1) << 3);
        As[px * 64 + ch2] = *(const uint4*)(Acm + ((size_t)b * IJ + qmap[px]) * 512 + ch * 8);
    }
    __syncthreads();
    int wv = tid >> 6, lane = tid & 63, r = lane & 15, g = lane >> 4;
    int q0 = wv * 32;
    f32x4 acc[2][2] = {{{0.f,0.f,0.f,0.f},{0.f,0.f,0.f,0.f}},{{0.f,0.f,0.f,0.f},{0.f,0.f,0.f,0.f}}};
    bf16x8 Bb[4][2], Aa[2][2];
#define Q1_LB(slot, it_) { const unsigned short* bp = Bw + (size_t)(q0 + r) * 512 + (it_) * 32 + g * 8; \
    Bb[slot][0] = *(const bf16x8*)bp; Bb[slot][1] = *(const bf16x8*)(bp + 16 * 512); }
#define Q1_LA(slot, it_) { int ch = (it_) * 4 + g; \
    int px0 = r, px1 = 16 + r; \
    Aa[slot][0] = *(const bf16x8*)&As[px0 * 64 + (ch ^ (px0 & 7) ^ (((px0 >> 3) & 1) << 3))]; \
    Aa[slot][1] = *(const bf16x8*)&As[px1 * 64 + (ch ^ (px1 & 7) ^ (((px1 >> 3) & 1) << 3))]; }
    Q1_LB(0, 0); Q1_LB(1, 1); Q1_LB(2, 2); Q1_LA(0, 0);
    #pragma unroll
    for (int it = 0; it < 16; ++it) {
        if (it + 3 < 16) Q1_LB((it + 3) & 3, it + 3);
        if (it + 1 < 16) Q1_LA((it + 1) & 1, it + 1);
        int s = it & 3, sa = it & 1;
        acc[0][0] = MFMA16(Aa[sa][0], Bb[s][0], acc[0][0]);
        acc[0][1] = MFMA16(Aa[sa][0], Bb[s][1], acc[0][1]);
        acc[1][0] = MFMA16(Aa[sa][1], Bb[s][0], acc[1][0]);
        acc[1][1] = MFMA16(Aa[sa][1], Bb[s][1], acc[1][1]);
    }
    float bi0 = bias[q0 + r], bi1 = bias[q0 + 16 + r];
    unsigned short* Pout = P1 + (size_t)b * PSTRIDE;
    #pragma unroll
    for (int mt = 0; mt < 2; ++mt)
        #pragma unroll
        for (int reg = 0; reg < 4; ++reg) {
            int px = mt * 16 + g * 4 + reg;
            if (m0 + px < NVALID) {
                int q = qmap[px];
                int i = q / 100, j = q - i * 100;
                size_t base = (size_t)((i + 1) * PADW + j + 1) * H2C;
                Pout[base + q0 + r]      = f2bf(fmaxf(acc[mt][0][reg] + bi0, 0.f));
                Pout[base + q0 + 16 + r] = f2bf(fmaxf(acc[mt][1][reg] + bi1, 0.f));
            }
        }
}

// ---------- 3x3 conv 128->128, pipelined; FQ4: fuse 1x1->2 + sigmoid ----------
template<int FQ4>
__global__ __launch_bounds__(256) void k_c3m(int in_off, int w_off,
                                             const float* __restrict__ bias,
                                             int out_off,
                                             const float* __restrict__ wq4,
                                             const float* __restrict__ bq4,
                                             float* __restrict__ out) {
    __shared__ uint4 As[1632];
    const unsigned short* Pin = (const unsigned short*)(g_buf + in_off);
    const unsigned short* wB  = (const unsigned short*)(g_buf + w_off);
    int jt = blockIdx.x, i = blockIdx.y, b = blockIdx.z;
    int j0 = (jt == 3) ? 68 : jt * 32;
    int tid = threadIdx.x;
    const unsigned short* Ab = Pin + (size_t)b * PSTRIDE;
    for (int idx = tid; idx < 1632; idx += 256) {
        int ky = idx / 544, rem = idx - ky * 544;
        int px = rem >> 4, ch = rem & 15;
        int ch2 = ch ^ (px & 7) ^ (((px >> 3) & 1) << 3);
        As[(ky * 34 + px) * 16 + ch2] =
            *(const uint4*)(Ab + (size_t)((i + ky) * PADW + j0 + px) * H2C + ch * 8);
    }
    __syncthreads();
    int wv = tid >> 6, lane = tid & 63, r = lane & 15, g = lane >> 4;
    int q0 = wv * 32;
    f32x4 acc[2][2] = {{{0.f,0.f,0.f,0.f},{0.f,0.f,0.f,0.f}},{{0.f,0.f,0.f,0.f},{0.f,0.f,0.f,0.f}}};
    bf16x8 Bb[4][2], Aa[2][2];
#define C3_LB(slot, it_) { int tap = (it_) >> 2, cc = (it_) & 3; \
    const unsigned short* bp = wB + (size_t)(q0 + r) * 1152 + tap * 128 + cc * 32 + g * 8; \
    Bb[slot][0] = *(const bf16x8*)bp; Bb[slot][1] = *(const bf16x8*)(bp + 16 * 1152); }
#define C3_LA(slot, it_) { int tap = (it_) >> 2, cc = (it_) & 3; \
    int ky = tap / 3, kx = tap - ky * 3; int ch = cc * 4 + g; \
    int px0 = r + kx, px1 = 16 + r + kx; \
    Aa[slot][0] = *(const bf16x8*)&As[(ky * 34 + px0) * 16 + (ch ^ (px0 & 7) ^ (((px0 >> 3) & 1) << 3))]; \
    Aa[slot][1] = *(const bf16x8*)&As[(ky * 34 + px1) * 16 + (ch ^ (px1 & 7) ^ (((px1 >> 3) & 1) << 3))]; }
    C3_LB(0, 0); C3_LB(1, 1); C3_LB(2, 2); C3_LA(0, 0);
    #pragma unroll
    for (int it = 0; it < 36; ++it) {
        if (it + 3 < 36) C3_LB((it + 3) & 3, it + 3);
        if (it + 1 < 36) C3_LA((it + 1) & 1, it + 1);
        int s = it & 3, sa = it & 1;
        acc[0][0] = MFMA16(Aa[sa][0], Bb[s][0], acc[0][0]);
        acc[0][1] = MFMA16(Aa[sa][0], Bb[s][1], acc[0][1]);
        acc[1][0] = MFMA16(Aa[sa][1], Bb[s][0], acc[1][0]);
        acc[1][1] = MFMA16(Aa[sa][1], Bb[s][1], acc[1][1]);
    }
    float bi0 = bias[q0 + r], bi1 = bias[q0 + 16 + r];
    if constexpr (!FQ4) {
        unsigned short* Ob = (unsigned short*)(g_buf + out_off) + (size_t)b * PSTRIDE;
        #pragma unroll
        for (int mt = 0; mt < 2; ++mt)
            #pragma unroll
            for (int reg = 0; reg < 4; ++reg) {
                int j = j0 + mt * 16 + g * 4 + reg;
                size_t base = (size_t)((i + 1) * PADW + j + 1) * H2C;
                Ob[base + q0 + r]      = f2bf(fmaxf(acc[mt][0][reg] + bi0, 0.f));
                Ob[base + q0 + 16 + r] = f2bf(fmaxf(acc[mt][1][reg] + bi1, 0.f));
            }
    } else {
        __shared__ float part[4][2][32];
        float w40a = wq4[q0 + r],       w40b = wq4[q0 + 16 + r];
        float w41a = wq4[128 + q0 + r], w41b = wq4[128 + q0 + 16 + r];
        #pragma unroll
        for (int mt = 0; mt < 2; ++mt)
            #pragma unroll
            for (int reg = 0; reg < 4; ++reg) {
                float x0 = fmaxf(acc[mt][0][reg] + bi0, 0.f);
                float x1 = fmaxf(acc[mt][1][reg] + bi1, 0.f);
                float p0 = x0 * w40a + x1 * w40b;
                float p1 = x0 * w41a + x1 * w41b;
                #pragma unroll
                for (int off = 1; off < 16; off <<= 1) {
                    p0 += __shfl_xor(p0, off);
                    p1 += __shfl_xor(p1, off);
                }
                if (r == 0) {
                    int px = mt * 16 + g * 4 + reg;
                    part[wv][0][px] = p0;
                    part[wv][1][px] = p1;
                }
            }
        __syncthreads();
        if (tid < 64) {
            int px = tid & 31, hd = tid >> 5;
            float s = part[0][hd][px] + part[1][hd][px] + part[2][hd][px] + part[3][hd][px]
                      + bq4[hd];
            out[(size_t)(b * 2 + hd) * IJ + i * 100 + (j0 + px)] = 1.f / (1.f + expf(-s));
        }
    }
}

extern "C" void kernel_launch(void* const* d_in, const int* in_sizes, int n_in,
                              void* d_out, int out_size, void* d_ws, size_t ws_size,
                              hipStream_t stream) {
    const float* x   = (const float*)d_in[0];
    const float* wb1 = (const float*)d_in[1];  const float* bb1 = (const float*)d_in[2];
    const float* wb2 = (const float*)d_in[3];  const float* bb2 = (const float*)d_in[4];
    const float* ws1 = (const float*)d_in[5];  const float* bs1 = (const float*)d_in[6];
    const float* ws2 = (const float*)d_in[7];  const float* bs2 = (const float*)d_in[8];
    const float* we1 = (const float*)d_in[9];  const float* be1 = (const float*)d_in[10];
    const float* we2 = (const float*)d_in[11]; const float* be2 = (const float*)d_in[12];
    const float* wp  = (const float*)d_in[13]; const float* bp  = (const float*)d_in[14];
    const float* w3d = (const float*)d_in[15]; const float* b3d = (const float*)d_in[16];
    const float* wq1 = (const float*)d_in[17]; const float* bq1 = (const float*)d_in[18];
    const float* wq2 = (const float*)d_in[19]; const float* bq2 = (const float*)d_in[20];
    const float* wq3 = (const float*)d_in[21]; const float* bq3 = (const float*)d_in[22];
    const float* wq4 = (const float*)d_in[23]; const float* bq4 = (const float*)d_in[24];
    float* out = (float*)d_out;

    k_prepw<<<512 + PREP_IDS / 256, 256, 0, stream>>>(wq1, wq2, wq3, x, b3d, bq1, w3d);
    k_conv_t<100, 64, 400><<<400, 128, 0, stream>>>(OFF_XT, wb1, bb1, OFF_H1);
    k_conv_t<64, 64, 256><<<400, 128, 0, stream>>>(OFF_H1, wb2, bb2, OFF_H2);
    k_sepf<<<600, 256, 0, stream>>>(ws1, bs1, we1, be1, wp, bp);
    k_amfh<<<1792 + 1250 + 2, 256, 0, stream>>>(ws2, bs2, we2, be2, out);
    k_bm2<<<dim3(20, 16, 2), 256, 0, stream>>>(b3d);
    k_q1m<<<dim3((NVALID + 31) / 32, 2), 256, 0, stream>>>(bq1);
    k_c3m<0><<<dim3(4, 100, 2), 256, 0, stream>>>(OFF_P1, OFF_WQ2B, bq2, OFF_P2,
                                                  nullptr, nullptr, nullptr);
    k_c3m<1><<<dim3(4, 100, 2), 256, 0, stream>>>(OFF_P2, OFF_WQ3B, bq3, 0,
                                                  wq4, bq4, out);
}